// Round 3
// baseline (1723.319 us; speedup 1.0000x reference)
//
#include <hip/hip_runtime.h>
#include <math.h>

#define NTOK 2048
#define NBF 266

typedef unsigned short u16;

__device__ __forceinline__ float bf2f(u16 u) {
  unsigned int x = ((unsigned int)u) << 16;
  return __uint_as_float(x);
}
__device__ __forceinline__ u16 f2bf(float f) {
  unsigned int x = __float_as_uint(f);
  unsigned int r = x + 0x7FFFu + ((x >> 16) & 1u);
  return (u16)(r >> 16);
}
__device__ __forceinline__ float wredsum64(float v) {
  for (int o = 32; o > 0; o >>= 1) v += __shfl_xor(v, o);
  return v;
}
__device__ __forceinline__ float bsum256(float v, float* red) {
  for (int o = 32; o > 0; o >>= 1) v += __shfl_xor(v, o);
  __syncthreads();
  if ((threadIdx.x & 63) == 0) red[threadIdx.x >> 6] = v;
  __syncthreads();
  return red[0] + red[1] + red[2] + red[3];
}
__device__ __forceinline__ float bmax256(float v, float* red) {
  for (int o = 32; o > 0; o >>= 1) v = fmaxf(v, __shfl_xor(v, o));
  __syncthreads();
  if ((threadIdx.x & 63) == 0) red[threadIdx.x >> 6] = v;
  __syncthreads();
  return fmaxf(fmaxf(red[0], red[1]), fmaxf(red[2], red[3]));
}
// inv_freq = 10000^(-2i/64); angle t = n * inv_freq (f32 mul like reference)
__device__ __forceinline__ void pos_sincos(int n, int i, float* s, float* c) {
  double invf = exp(-(double)(2 * i) / 64.0 * 9.210340371976184);
  float t = (float)n * (float)invf;
  *s = sinf(t);
  *c = cosf(t);
}

// ---------------- prep: x, LN1, K/V all heads, rotary(Kg), diag, Vg mask ----
__global__ __launch_bounds__(64) void k_prep(
    const int* __restrict__ ids, const float* __restrict__ tok_emb,
    const float* __restrict__ ln1g, const float* __restrict__ ln1b,
    const float* __restrict__ Wk, const float* __restrict__ Wv,
    u16* __restrict__ Kg, u16* __restrict__ Vg,
    u16* __restrict__ Kl, u16* __restrict__ Vl,
    float* __restrict__ diagK, float* __restrict__ x0) {
  int bn = blockIdx.x;
  int b = bn >> 11, n = bn & (NTOK - 1);
  int t = threadIdx.x;
  __shared__ float hn[64];
  int id = ids[bn];
  float pv;
  {
    int i = (t < 32) ? t : (t - 32);
    float s, c;
    pos_sincos(n, i, &s, &c);
    pv = (t < 32) ? s : c;
  }
  float xv = tok_emb[id * 64 + t] + pv;
  float mu = wredsum64(xv) * 0.015625f;
  float dv = xv - mu;
  float var = wredsum64(dv * dv) * 0.015625f;
  float rstd = rsqrtf(var + 1e-5f);
  hn[t] = dv * rstd * ln1g[t] + ln1b[t];
  if (n == 0) x0[b * 64 + t] = xv;
  __syncthreads();

  float ka[8] = {0, 0, 0, 0, 0, 0, 0, 0};
  float va[8] = {0, 0, 0, 0, 0, 0, 0, 0};
  const float* wk = Wk + t * 8;
  const float* wv = Wv + t * 8;
#pragma unroll 4
  for (int d2 = 0; d2 < 64; ++d2) {
    float hv = hn[d2];
    float4 k0 = *reinterpret_cast<const float4*>(wk + d2 * 512);
    float4 k1 = *reinterpret_cast<const float4*>(wk + d2 * 512 + 4);
    float4 v0 = *reinterpret_cast<const float4*>(wv + d2 * 512);
    float4 v1 = *reinterpret_cast<const float4*>(wv + d2 * 512 + 4);
    ka[0] += hv * k0.x; ka[1] += hv * k0.y; ka[2] += hv * k0.z; ka[3] += hv * k0.w;
    ka[4] += hv * k1.x; ka[5] += hv * k1.y; ka[6] += hv * k1.z; ka[7] += hv * k1.w;
    va[0] += hv * v0.x; va[1] += hv * v0.y; va[2] += hv * v0.z; va[3] += hv * v0.w;
    va[4] += hv * v1.x; va[5] += hv * v1.y; va[6] += hv * v1.z; va[7] += hv * v1.w;
  }
  int j = t >> 3;                 // head
  int db = (t & 7) * 8;           // d offset within head
  float maskf = (id != 0) ? 1.f : 0.f;
  if (j < 4) {                    // global heads: rotary K, diag, masked Vg
    float kr[8];
#pragma unroll
    for (int p = 0; p < 4; ++p) {
      float s, c;
      pos_sincos(n, (db >> 1) + p, &s, &c);
      float e0 = ka[2 * p], e1 = ka[2 * p + 1];
      kr[2 * p] = e0 * c - e1 * s;
      kr[2 * p + 1] = e1 * c + e0 * s;
    }
    float dq = 0;
#pragma unroll
    for (int i = 0; i < 8; ++i) dq += kr[i] * kr[i];
    dq += __shfl_xor(dq, 1);
    dq += __shfl_xor(dq, 2);
    dq += __shfl_xor(dq, 4);
    size_t hb = (size_t)(b * 4 + j) * NTOK + n;
    if ((t & 7) == 0) diagK[hb] = dq * 0.0625f;  // 0.5*dn*dn = 1/16
    size_t base = hb * 64 + db;
    ushort4 s0, s1;
    s0.x = f2bf(kr[0]); s0.y = f2bf(kr[1]); s0.z = f2bf(kr[2]); s0.w = f2bf(kr[3]);
    s1.x = f2bf(kr[4]); s1.y = f2bf(kr[5]); s1.z = f2bf(kr[6]); s1.w = f2bf(kr[7]);
    *reinterpret_cast<ushort4*>(Kg + base) = s0;
    *reinterpret_cast<ushort4*>(Kg + base + 4) = s1;
    ushort4 m0, m1;
    m0.x = f2bf(va[0] * maskf); m0.y = f2bf(va[1] * maskf);
    m0.z = f2bf(va[2] * maskf); m0.w = f2bf(va[3] * maskf);
    m1.x = f2bf(va[4] * maskf); m1.y = f2bf(va[5] * maskf);
    m1.z = f2bf(va[6] * maskf); m1.w = f2bf(va[7] * maskf);
    *reinterpret_cast<ushort4*>(Vg + base) = m0;
    *reinterpret_cast<ushort4*>(Vg + base + 4) = m1;
  } else {                        // local heads: raw K, raw V
    size_t base = ((size_t)(b * 4 + (j - 4)) * NTOK + n) * 64 + db;
    ushort4 s0, s1, v0, v1;
    s0.x = f2bf(ka[0]); s0.y = f2bf(ka[1]); s0.z = f2bf(ka[2]); s0.w = f2bf(ka[3]);
    s1.x = f2bf(ka[4]); s1.y = f2bf(ka[5]); s1.z = f2bf(ka[6]); s1.w = f2bf(ka[7]);
    v0.x = f2bf(va[0]); v0.y = f2bf(va[1]); v0.z = f2bf(va[2]); v0.w = f2bf(va[3]);
    v1.x = f2bf(va[4]); v1.y = f2bf(va[5]); v1.z = f2bf(va[6]); v1.w = f2bf(va[7]);
    *reinterpret_cast<ushort4*>(Kl + base) = s0;
    *reinterpret_cast<ushort4*>(Kl + base + 4) = s1;
    *reinterpret_cast<ushort4*>(Vl + base) = v0;
    *reinterpret_cast<ushort4*>(Vl + base + 4) = v1;
  }
}

// ---------------- global max over dash = dn * Kg @ proj^T --------------------
__global__ __launch_bounds__(256) void k_max(
    const u16* __restrict__ Kg, const float* __restrict__ proj,
    unsigned int* __restrict__ gmax) {
  int bh = blockIdx.x;
  int n0 = blockIdx.y * 64;
  __shared__ float kg[4096];
  __shared__ float red[4];
  size_t base = ((size_t)bh * NTOK + n0) * 64;
  for (int idx = threadIdx.x; idx < 4096; idx += 256) kg[idx] = bf2f(Kg[base + idx]);
  __syncthreads();
  float mv = -3e38f;
  for (int m = threadIdx.x; m < NBF; m += 256) {
    float pr[64];
    const float* pp = proj + m * 64;
#pragma unroll
    for (int d = 0; d < 64; d += 4) {
      float4 u = *reinterpret_cast<const float4*>(pp + d);
      pr[d] = u.x; pr[d + 1] = u.y; pr[d + 2] = u.z; pr[d + 3] = u.w;
    }
    for (int r = 0; r < 64; ++r) {
      float s = 0;
#pragma unroll 8
      for (int d = 0; d < 64; ++d) s += kg[r * 64 + d] * pr[d];
      mv = fmaxf(mv, s);
    }
  }
  mv *= 0.35355339059327373f;  // dn > 0 so max commutes
  for (int o = 32; o > 0; o >>= 1) mv = fmaxf(mv, __shfl_xor(mv, o));
  if ((threadIdx.x & 63) == 0) red[threadIdx.x >> 6] = mv;
  __syncthreads();
  if (threadIdx.x == 0) {
    float m2 = fmaxf(fmaxf(red[0], red[1]), fmaxf(red[2], red[3]));
    unsigned int b = __float_as_uint(m2);
    unsigned int u = (b & 0x80000000u) ? ~b : (b | 0x80000000u);
    atomicMax(gmax, u);
  }
}

// ---------------- ctx = kp^T @ Vg, ksum = sum_n kp ---------------------------
__global__ __launch_bounds__(256) void k_ctx(
    const u16* __restrict__ Kg, const u16* __restrict__ Vg,
    const float* __restrict__ diagK, const float* __restrict__ proj,
    const unsigned int* __restrict__ gmax,
    float* __restrict__ ctx, float* __restrict__ ksum) {
  int bh = blockIdx.x;
  int m0 = blockIdx.y * 64;
  int ns = blockIdx.z;
  __shared__ float prj[64 * 65];
  __shared__ float kg4[4 * 64], vg4[4 * 64], kp4[4 * 64], dg4[4];
  int t = threadIdx.x;
  for (int idx = t; idx < 4096; idx += 256) {
    int r = idx >> 6, d = idx & 63;
    int m = m0 + r;
    prj[r * 65 + d] = (m < NBF) ? proj[m * 64 + d] : 0.f;
  }
  unsigned int u = *gmax;
  unsigned int bb = (u & 0x80000000u) ? (u & 0x7FFFFFFFu) : ~u;
  float mx = __uint_as_float(bb);
  const float dn = 0.35355339059327373f;
  const float ratio = 1.0f / sqrtf(266.0f);
  float acc[16];
#pragma unroll
  for (int i = 0; i < 16; ++i) acc[i] = 0.f;
  float ks = 0.f;
  int ml = t & 63, wg = t >> 6;
  int n0 = ns * 256;
  for (int nn = n0; nn < n0 + 256; nn += 4) {
    __syncthreads();
    {
      int r = t >> 6, d = t & 63;
      size_t gi = ((size_t)bh * NTOK + nn + r) * 64 + d;
      kg4[t] = bf2f(Kg[gi]);
      vg4[t] = bf2f(Vg[gi]);
      if (t < 4) dg4[t] = diagK[(size_t)bh * NTOK + nn + t];
    }
    __syncthreads();
    {
      float s = 0;
#pragma unroll 8
      for (int d = 0; d < 64; ++d) s += kg4[wg * 64 + d] * prj[ml * 65 + d];
      float dash = dn * s;
      int m = m0 + ml;
      kp4[wg * 64 + ml] = (m < NBF) ? ratio * (expf(dash - dg4[wg] - mx) + 1e-4f) : 0.f;
    }
    __syncthreads();
#pragma unroll
    for (int r = 0; r < 4; ++r) {
      float kv = kp4[r * 64 + ml];
      if (wg == 0) ks += kv;
      const float* vrow = &vg4[r * 64 + wg * 16];
#pragma unroll
      for (int dd = 0; dd < 16; ++dd) acc[dd] += kv * vrow[dd];
    }
  }
  int m = m0 + ml;
  if (m < NBF) {
    float* cp = &ctx[((size_t)bh * NBF + m) * 64 + wg * 16];
#pragma unroll
    for (int dd = 0; dd < 16; ++dd) atomicAdd(&cp[dd], acc[dd]);
    if (wg == 0) atomicAdd(&ksum[(size_t)bh * NBF + m], ks);
  }
}

// ---------------- everything at position 0 ----------------------------------
__global__ __launch_bounds__(256) void k_fin(
    const int* __restrict__ ids,
    const float* __restrict__ ln1g, const float* __restrict__ ln1b,
    const float* __restrict__ Wq, const float* __restrict__ Wo,
    const float* __restrict__ ln2g, const float* __restrict__ ln2b,
    const float* __restrict__ W1, const float* __restrict__ b1,
    const float* __restrict__ W2, const float* __restrict__ b2,
    const float* __restrict__ lnfg, const float* __restrict__ lnfb,
    const float* __restrict__ Wout, const float* __restrict__ bout,
    const float* __restrict__ Wc1, const float* __restrict__ bc1,
    const float* __restrict__ Wc2, const float* __restrict__ bc2,
    const float* __restrict__ proj,
    const u16* __restrict__ Kl, const u16* __restrict__ Vl,
    const float* __restrict__ ctx, const float* __restrict__ ksum,
    const float* __restrict__ x0, float* __restrict__ out) {
  int b = blockIdx.x;
  int t = threadIdx.x;
  __shared__ float x0s[64], hn1[64], q[512], buf[288], o512[512];
  __shared__ float dots[2048], pol[4][64], red[4];
  __shared__ float y1[64], hn2[64], gact[256], hfin[64], repS[64], c1s[32];
  const float dn = 0.35355339059327373f;
  const float ratio = 1.0f / sqrtf(266.0f);

  if (t < 64) {  // LN1 at position 0
    float xv = x0[b * 64 + t];
    x0s[t] = xv;
    float mu = wredsum64(xv) * 0.015625f;
    float dv = xv - mu;
    float var = wredsum64(dv * dv) * 0.015625f;
    hn1[t] = dv * rsqrtf(var + 1e-5f) * ln1g[t] + ln1b[t];
  }
  __syncthreads();
  for (int c = t; c < 512; c += 256) {  // q row (rotary at n=0 is identity)
    float s = 0;
    for (int d = 0; d < 64; ++d) s += hn1[d] * Wq[d * 512 + c];
    q[c] = s;
  }
  __syncthreads();

  // global heads
  for (int h = 0; h < 4; ++h) {
    float dq = 0;
    for (int d = 0; d < 64; ++d) {
      float qv = q[h * 64 + d];
      dq += qv * qv;
    }
    dq *= 0.0625f;
    float lmax = -3e38f;
    for (int m = t; m < NBF; m += 256) {
      const float* pp = proj + m * 64;
      float s = 0;
#pragma unroll
      for (int d4 = 0; d4 < 16; ++d4) {
        float4 uu = *reinterpret_cast<const float4*>(pp + d4 * 4);
        s += q[h * 64 + d4 * 4] * uu.x + q[h * 64 + d4 * 4 + 1] * uu.y +
             q[h * 64 + d4 * 4 + 2] * uu.z + q[h * 64 + d4 * 4 + 3] * uu.w;
      }
      float dash = dn * s;
      buf[m] = dash;
      lmax = fmaxf(lmax, dash);
    }
    float mxq = bmax256(lmax, red);
    for (int m = t; m < NBF; m += 256)
      buf[m] = ratio * (expf(buf[m] - dq - mxq) + 1e-4f);
    __syncthreads();
    float part = 0;
    for (int m = t; m < NBF; m += 256) part += buf[m] * ksum[(b * 4 + h) * NBF + m];
    float den = bsum256(part, red);
    {
      int d = t & 63, mg = t >> 6;
      float s = 0;
      for (int m = mg; m < NBF; m += 4)
        s += buf[m] * ctx[(((size_t)(b * 4 + h)) * NBF + m) * 64 + d];
      pol[mg][d] = s;
    }
    __syncthreads();
    if (t < 64) o512[h * 64 + t] = (pol[0][t] + pol[1][t] + pol[2][t] + pol[3][t]) / den;
    __syncthreads();
  }

  // local heads (softmax attention, query row 0 only)
  for (int h = 0; h < 4; ++h) {
    size_t base = (size_t)(b * 4 + h) * NTOK;
    float lmax = -3e38f;
    for (int n1 = t; n1 < NTOK; n1 += 256) {
      const ushort4* kr4 = reinterpret_cast<const ushort4*>(Kl + (base + n1) * 64);
      float s = 0;
#pragma unroll
      for (int d4 = 0; d4 < 16; ++d4) {
        ushort4 uu = kr4[d4];
        s += q[(4 + h) * 64 + d4 * 4] * bf2f(uu.x) +
             q[(4 + h) * 64 + d4 * 4 + 1] * bf2f(uu.y) +
             q[(4 + h) * 64 + d4 * 4 + 2] * bf2f(uu.z) +
             q[(4 + h) * 64 + d4 * 4 + 3] * bf2f(uu.w);
      }
      float dv = s * 0.125f;
      if (ids[b * NTOK + n1] == 0) dv = -1e9f;
      dots[n1] = dv;
      lmax = fmaxf(lmax, dv);
    }
    float mxl = bmax256(lmax, red);
    float ps = 0;
    for (int n1 = t; n1 < NTOK; n1 += 256) {
      float p = expf(dots[n1] - mxl);
      dots[n1] = p;
      ps += p;
    }
    float sden = bsum256(ps, red);
    {
      int d = t & 63, ng = t >> 6;
      float s = 0;
      for (int n1 = ng; n1 < NTOK; n1 += 4)
        s += dots[n1] * bf2f(Vl[(base + n1) * 64 + d]);
      pol[ng][d] = s;
    }
    __syncthreads();
    if (t < 64)
      o512[(4 + h) * 64 + t] = (pol[0][t] + pol[1][t] + pol[2][t] + pol[3][t]) / sden;
    __syncthreads();
  }

  // Wo, residual, FF, final LN, heads
  if (t < 64) {
    float s = 0;
    for (int c = 0; c < 512; ++c) s += o512[c] * Wo[c * 64 + t];
    float yv = x0s[t] + s;
    y1[t] = yv;
    float mu = wredsum64(yv) * 0.015625f;
    float dv = yv - mu;
    float var = wredsum64(dv * dv) * 0.015625f;
    hn2[t] = dv * rsqrtf(var + 1e-5f) * ln2g[t] + ln2b[t];
  }
  __syncthreads();
  {
    float s = b1[t];
    for (int d = 0; d < 64; ++d) s += hn2[d] * W1[d * 256 + t];
    gact[t] = 0.5f * s * (1.f + erff(s * 0.7071067811865475f));  // exact gelu
  }
  __syncthreads();
  if (t < 64) {
    float s = b2[t];
    for (int jj = 0; jj < 256; ++jj) s += gact[jj] * W2[jj * 64 + t];
    float y2 = x0s[t] + s;
    float hm = 0.5f * (y1[t] + y2);
    float mu = wredsum64(hm) * 0.015625f;
    float dv = hm - mu;
    float var = wredsum64(dv * dv) * 0.015625f;
    hfin[t] = dv * rsqrtf(var + 1e-5f) * lnfg[t] + lnfb[t];
  }
  __syncthreads();
  if (t < 64) {
    float s = bout[t];
    for (int d = 0; d < 64; ++d) s += hfin[d] * Wout[d * 64 + t];
    repS[t] = s;
    out[16 + b * 64 + t] = s;  // rep output (f32)
  }
  __syncthreads();
  if (t < 32) {
    float s = bc1[t];
    for (int d = 0; d < 64; ++d) s += repS[d] * Wc1[d * 32 + t];
    c1s[t] = fmaxf(s, 0.f);
  }
  __syncthreads();
  if (t < 2) {
    float s = bc2[t];
    for (int jj = 0; jj < 32; ++jj) s += c1s[jj] * Wc2[jj * 2 + t];
    out[b * 2 + t] = s;  // classifier output (f32)
  }
}

extern "C" void kernel_launch(void* const* d_in, const int* in_sizes, int n_in,
                              void* d_out, int out_size, void* d_ws, size_t ws_size,
                              hipStream_t stream) {
  (void)in_sizes; (void)n_in; (void)out_size; (void)ws_size;
  const int* ids = (const int*)d_in[0];
  const float* tok = (const float*)d_in[1];
  const float* ln1g = (const float*)d_in[2];
  const float* ln1b = (const float*)d_in[3];
  const float* Wq = (const float*)d_in[4];
  const float* Wk = (const float*)d_in[5];
  const float* Wv = (const float*)d_in[6];
  const float* Wo = (const float*)d_in[7];
  const float* ln2g = (const float*)d_in[8];
  const float* ln2b = (const float*)d_in[9];
  const float* W1 = (const float*)d_in[10];
  const float* b1 = (const float*)d_in[11];
  const float* W2 = (const float*)d_in[12];
  const float* b2 = (const float*)d_in[13];
  const float* lnfg = (const float*)d_in[14];
  const float* lnfb = (const float*)d_in[15];
  const float* Wout = (const float*)d_in[16];
  const float* bout = (const float*)d_in[17];
  const float* Wc1 = (const float*)d_in[18];
  const float* bc1 = (const float*)d_in[19];
  const float* Wc2 = (const float*)d_in[20];
  const float* bc2 = (const float*)d_in[21];
  const float* proj = (const float*)d_in[22];

  uint8_t* w = (uint8_t*)d_ws;
  size_t off = 0;
  const size_t big = (size_t)8 * 4 * NTOK * 64 * 2;  // 8.39 MB each
  u16* Kg = (u16*)(w + off); off += big;
  u16* Vg = (u16*)(w + off); off += big;
  u16* Kl = (u16*)(w + off); off += big;
  u16* Vl = (u16*)(w + off); off += big;
  float* diagK = (float*)(w + off); off += (size_t)8 * 4 * NTOK * 4;
  float* ctx = (float*)(w + off); off += (size_t)8 * 4 * NBF * 64 * 4;
  float* ksum = (float*)(w + off); off += (size_t)8 * 4 * NBF * 4;
  unsigned int* gmax = (unsigned int*)(w + off); off += 4;
  float* x0 = (float*)(w + off); off += 64 * 8 * 4;

  // zero accumulators + gmax (contiguous: ctx, ksum, gmax)
  hipMemsetAsync(ctx, 0,
                 (size_t)8 * 4 * NBF * 64 * 4 + (size_t)8 * 4 * NBF * 4 + 4, stream);
  k_prep<<<8 * NTOK, 64, 0, stream>>>(ids, tok, ln1g, ln1b, Wk, Wv, Kg, Vg, Kl, Vl,
                                      diagK, x0);
  k_max<<<dim3(32, 32), 256, 0, stream>>>(Kg, proj, gmax);
  k_ctx<<<dim3(32, 5, 8), 256, 0, stream>>>(Kg, Vg, diagK, proj, gmax, ctx, ksum);
  k_fin<<<8, 256, 0, stream>>>(ids, ln1g, ln1b, Wq, Wo, ln2g, ln2b, W1, b1, W2, b2,
                               lnfg, lnfb, Wout, bout, Wc1, bc1, Wc2, bc2, proj,
                               Kl, Vl, ctx, ksum, x0, (float*)d_out);
}

// Round 4
// 1159.538 us; speedup vs baseline: 1.4862x; 1.4862x over previous
//
#include <hip/hip_runtime.h>
#include <math.h>

#define NTOK 2048
#define NBF 266

typedef unsigned short u16;

__device__ __forceinline__ float bf2f(u16 u) {
  unsigned int x = ((unsigned int)u) << 16;
  return __uint_as_float(x);
}
__device__ __forceinline__ u16 f2bf(float f) {
  unsigned int x = __float_as_uint(f);
  unsigned int r = x + 0x7FFFu + ((x >> 16) & 1u);
  return (u16)(r >> 16);
}
__device__ __forceinline__ float wredsum64(float v) {
  for (int o = 32; o > 0; o >>= 1) v += __shfl_xor(v, o);
  return v;
}
__device__ __forceinline__ float bsum256(float v, float* red) {
  for (int o = 32; o > 0; o >>= 1) v += __shfl_xor(v, o);
  __syncthreads();
  if ((threadIdx.x & 63) == 0) red[threadIdx.x >> 6] = v;
  __syncthreads();
  return red[0] + red[1] + red[2] + red[3];
}
__device__ __forceinline__ float bmax256(float v, float* red) {
  for (int o = 32; o > 0; o >>= 1) v = fmaxf(v, __shfl_xor(v, o));
  __syncthreads();
  if ((threadIdx.x & 63) == 0) red[threadIdx.x >> 6] = v;
  __syncthreads();
  return fmaxf(fmaxf(red[0], red[1]), fmaxf(red[2], red[3]));
}
// inv_freq[i] = 10000^(-i/32) = 2^(-i*log2(1e4)/32), i in [0,32)
#define INVF_C 0.4152410118609190f

// ---------------- prep: x, LN1, K/V all heads, rotary(Kg), diag, Vg mask ----
// 4 tokens per 64-thread block: weight traffic /4, f32 transcendentals only.
__global__ __launch_bounds__(64) void k_prep(
    const int* __restrict__ ids, const float* __restrict__ tok_emb,
    const float* __restrict__ ln1g, const float* __restrict__ ln1b,
    const float* __restrict__ Wk, const float* __restrict__ Wv,
    u16* __restrict__ Kg, u16* __restrict__ Vg,
    u16* __restrict__ Kl, u16* __restrict__ Vl,
    float* __restrict__ diagK, float* __restrict__ x0) {
  int blk = blockIdx.x;            // 8 * 512 blocks
  int b = blk >> 9, nt = blk & 511;
  int n0 = nt * 4;
  int t = threadIdx.x;
  __shared__ float hn[4][64];
  int idv[4];
  float g = ln1g[t], bb = ln1b[t];
#pragma unroll
  for (int j = 0; j < 4; ++j) {
    int n = n0 + j;
    int id = ids[b * NTOK + n];
    idv[j] = id;
    float ang = (float)n * exp2f(-INVF_C * (float)(t & 31));
    float pv = (t < 32) ? sinf(ang) : cosf(ang);
    float xv = tok_emb[id * 64 + t] + pv;
    float mu = wredsum64(xv) * 0.015625f;
    float dv = xv - mu;
    float var = wredsum64(dv * dv) * 0.015625f;
    hn[j][t] = dv * rsqrtf(var + 1e-5f) * g + bb;
    if (n == 0) x0[b * 64 + t] = xv;
  }
  __syncthreads();

  float ka[4][8], va[4][8];
#pragma unroll
  for (int j = 0; j < 4; ++j)
#pragma unroll
    for (int i = 0; i < 8; ++i) { ka[j][i] = 0.f; va[j][i] = 0.f; }
  const float* wk = Wk + t * 8;
  const float* wv = Wv + t * 8;
  for (int d2 = 0; d2 < 64; ++d2) {
    float4 k0 = *reinterpret_cast<const float4*>(wk + d2 * 512);
    float4 k1 = *reinterpret_cast<const float4*>(wk + d2 * 512 + 4);
    float4 v0 = *reinterpret_cast<const float4*>(wv + d2 * 512);
    float4 v1 = *reinterpret_cast<const float4*>(wv + d2 * 512 + 4);
#pragma unroll
    for (int j = 0; j < 4; ++j) {
      float hv = hn[j][d2];
      ka[j][0] += hv * k0.x; ka[j][1] += hv * k0.y;
      ka[j][2] += hv * k0.z; ka[j][3] += hv * k0.w;
      ka[j][4] += hv * k1.x; ka[j][5] += hv * k1.y;
      ka[j][6] += hv * k1.z; ka[j][7] += hv * k1.w;
      va[j][0] += hv * v0.x; va[j][1] += hv * v0.y;
      va[j][2] += hv * v0.z; va[j][3] += hv * v0.w;
      va[j][4] += hv * v1.x; va[j][5] += hv * v1.y;
      va[j][6] += hv * v1.z; va[j][7] += hv * v1.w;
    }
  }

  int jh = t >> 3;                // head
  int db = (t & 7) * 8;           // d offset within head
#pragma unroll
  for (int j = 0; j < 4; ++j) {
    int n = n0 + j;
    float maskf = (idv[j] != 0) ? 1.f : 0.f;
    if (jh < 4) {                 // global heads: rotary K, diag, masked Vg
      float kr[8];
#pragma unroll
      for (int p = 0; p < 4; ++p) {
        int q = (db >> 1) + p;
        float ang = (float)n * exp2f(-INVF_C * (float)q);
        float sv = sinf(ang), cv = cosf(ang);
        float e0 = ka[j][2 * p], e1 = ka[j][2 * p + 1];
        kr[2 * p] = e0 * cv - e1 * sv;
        kr[2 * p + 1] = e1 * cv + e0 * sv;
      }
      float dq = 0;
#pragma unroll
      for (int i = 0; i < 8; ++i) dq += kr[i] * kr[i];
      dq += __shfl_xor(dq, 1);
      dq += __shfl_xor(dq, 2);
      dq += __shfl_xor(dq, 4);
      size_t hb = (size_t)(b * 4 + jh) * NTOK + n;
      if ((t & 7) == 0) diagK[hb] = dq * 0.0625f;  // 0.5*dn*dn = 1/16
      size_t base = hb * 64 + db;
      ushort4 s0, s1;
      s0.x = f2bf(kr[0]); s0.y = f2bf(kr[1]); s0.z = f2bf(kr[2]); s0.w = f2bf(kr[3]);
      s1.x = f2bf(kr[4]); s1.y = f2bf(kr[5]); s1.z = f2bf(kr[6]); s1.w = f2bf(kr[7]);
      *reinterpret_cast<ushort4*>(Kg + base) = s0;
      *reinterpret_cast<ushort4*>(Kg + base + 4) = s1;
      ushort4 m0, m1;
      m0.x = f2bf(va[j][0] * maskf); m0.y = f2bf(va[j][1] * maskf);
      m0.z = f2bf(va[j][2] * maskf); m0.w = f2bf(va[j][3] * maskf);
      m1.x = f2bf(va[j][4] * maskf); m1.y = f2bf(va[j][5] * maskf);
      m1.z = f2bf(va[j][6] * maskf); m1.w = f2bf(va[j][7] * maskf);
      *reinterpret_cast<ushort4*>(Vg + base) = m0;
      *reinterpret_cast<ushort4*>(Vg + base + 4) = m1;
    } else {                      // local heads: raw K, raw V
      size_t base = ((size_t)(b * 4 + (jh - 4)) * NTOK + n) * 64 + db;
      ushort4 s0, s1, v0, v1;
      s0.x = f2bf(ka[j][0]); s0.y = f2bf(ka[j][1]);
      s0.z = f2bf(ka[j][2]); s0.w = f2bf(ka[j][3]);
      s1.x = f2bf(ka[j][4]); s1.y = f2bf(ka[j][5]);
      s1.z = f2bf(ka[j][6]); s1.w = f2bf(ka[j][7]);
      v0.x = f2bf(va[j][0]); v0.y = f2bf(va[j][1]);
      v0.z = f2bf(va[j][2]); v0.w = f2bf(va[j][3]);
      v1.x = f2bf(va[j][4]); v1.y = f2bf(va[j][5]);
      v1.z = f2bf(va[j][6]); v1.w = f2bf(va[j][7]);
      *reinterpret_cast<ushort4*>(Kl + base) = s0;
      *reinterpret_cast<ushort4*>(Kl + base + 4) = s1;
      *reinterpret_cast<ushort4*>(Vl + base) = v0;
      *reinterpret_cast<ushort4*>(Vl + base + 4) = v1;
    }
  }
}

// ---------------- global max over dash = dn * Kg @ proj^T --------------------
// proj row held in 16 float4 REGISTERS (full static unroll -> no scratch).
__global__ __launch_bounds__(256) void k_max(
    const u16* __restrict__ Kg, const float* __restrict__ proj,
    unsigned int* __restrict__ gmax) {
  int bh = blockIdx.x;
  int n0 = blockIdx.y * 64;
  __shared__ float4 kg[1024];  // 64 rows x 16 float4
  __shared__ float red[4];
  size_t base = ((size_t)bh * NTOK + n0) * 64;
  const ushort4* src = reinterpret_cast<const ushort4*>(Kg + base);
  for (int i = threadIdx.x; i < 1024; i += 256) {
    ushort4 u = src[i];
    kg[i] = make_float4(bf2f(u.x), bf2f(u.y), bf2f(u.z), bf2f(u.w));
  }
  __syncthreads();
  float mv = -3e38f;
  for (int m = threadIdx.x; m < NBF; m += 256) {
    float4 pr[16];
    const float4* pp = reinterpret_cast<const float4*>(proj + m * 64);
#pragma unroll
    for (int q = 0; q < 16; ++q) pr[q] = pp[q];
    for (int r = 0; r < 64; ++r) {
      float s = 0;
#pragma unroll
      for (int q = 0; q < 16; ++q) {
        float4 gg = kg[r * 16 + q];
        s += gg.x * pr[q].x + gg.y * pr[q].y + gg.z * pr[q].z + gg.w * pr[q].w;
      }
      mv = fmaxf(mv, s);
    }
  }
  mv *= 0.35355339059327373f;  // dn > 0 so max commutes
  for (int o = 32; o > 0; o >>= 1) mv = fmaxf(mv, __shfl_xor(mv, o));
  if ((threadIdx.x & 63) == 0) red[threadIdx.x >> 6] = mv;
  __syncthreads();
  if (threadIdx.x == 0) {
    float m2 = fmaxf(fmaxf(red[0], red[1]), fmaxf(red[2], red[3]));
    unsigned int b = __float_as_uint(m2);
    unsigned int u = (b & 0x80000000u) ? ~b : (b | 0x80000000u);
    atomicMax(gmax, u);
  }
}

// ---------------- ctx = kp^T @ Vg, ksum = sum_n kp ---------------------------
__global__ __launch_bounds__(256) void k_ctx(
    const u16* __restrict__ Kg, const u16* __restrict__ Vg,
    const float* __restrict__ diagK, const float* __restrict__ proj,
    const unsigned int* __restrict__ gmax,
    float* __restrict__ ctx, float* __restrict__ ksum) {
  int bh = blockIdx.x;
  int m0 = blockIdx.y * 64;
  int ns = blockIdx.z;
  __shared__ float prj[64 * 66];
  __shared__ float kg4[4 * 64], vg4[4 * 64], kp4[4 * 64], dg4[4];
  int t = threadIdx.x;
  for (int idx = t; idx < 4096; idx += 256) {
    int r = idx >> 6, d = idx & 63;
    int m = m0 + r;
    prj[r * 66 + d] = (m < NBF) ? proj[m * 64 + d] : 0.f;
  }
  unsigned int u = *gmax;
  unsigned int bb = (u & 0x80000000u) ? (u & 0x7FFFFFFFu) : ~u;
  float mx = __uint_as_float(bb);
  const float dn = 0.35355339059327373f;
  const float ratio = 1.0f / sqrtf(266.0f);
  float acc[16];
#pragma unroll
  for (int i = 0; i < 16; ++i) acc[i] = 0.f;
  float ks = 0.f;
  int ml = t & 63, wg = t >> 6;
  int n0 = ns * 256;
  for (int nn = n0; nn < n0 + 256; nn += 4) {
    __syncthreads();
    {
      int r = t >> 6, d = t & 63;
      size_t gi = ((size_t)bh * NTOK + nn + r) * 64 + d;
      kg4[t] = bf2f(Kg[gi]);
      vg4[t] = bf2f(Vg[gi]);
      if (t < 4) dg4[t] = diagK[(size_t)bh * NTOK + nn + t];
    }
    __syncthreads();
    {
      float s = 0;
      const float2* kk = reinterpret_cast<const float2*>(&kg4[wg * 64]);
      const float2* pp = reinterpret_cast<const float2*>(&prj[ml * 66]);
#pragma unroll
      for (int d2 = 0; d2 < 32; ++d2) {
        float2 a = kk[d2], p = pp[d2];
        s += a.x * p.x + a.y * p.y;
      }
      float dash = dn * s;
      int m = m0 + ml;
      kp4[wg * 64 + ml] = (m < NBF) ? ratio * (expf(dash - dg4[wg] - mx) + 1e-4f) : 0.f;
    }
    __syncthreads();
#pragma unroll
    for (int r = 0; r < 4; ++r) {
      float kv = kp4[r * 64 + ml];
      if (wg == 0) ks += kv;
      const float4* vrow = reinterpret_cast<const float4*>(&vg4[r * 64 + wg * 16]);
#pragma unroll
      for (int dd = 0; dd < 4; ++dd) {
        float4 vv = vrow[dd];
        acc[dd * 4 + 0] += kv * vv.x;
        acc[dd * 4 + 1] += kv * vv.y;
        acc[dd * 4 + 2] += kv * vv.z;
        acc[dd * 4 + 3] += kv * vv.w;
      }
    }
  }
  int m = m0 + ml;
  if (m < NBF) {
    float* cp = &ctx[((size_t)bh * NBF + m) * 64 + wg * 16];
#pragma unroll
    for (int dd = 0; dd < 16; ++dd) atomicAdd(&cp[dd], acc[dd]);
    if (wg == 0) atomicAdd(&ksum[(size_t)bh * NBF + m], ks);
  }
}

// ---------------- everything at position 0 ----------------------------------
__global__ __launch_bounds__(256) void k_fin(
    const int* __restrict__ ids,
    const float* __restrict__ ln1g, const float* __restrict__ ln1b,
    const float* __restrict__ Wq, const float* __restrict__ Wo,
    const float* __restrict__ ln2g, const float* __restrict__ ln2b,
    const float* __restrict__ W1, const float* __restrict__ b1,
    const float* __restrict__ W2, const float* __restrict__ b2,
    const float* __restrict__ lnfg, const float* __restrict__ lnfb,
    const float* __restrict__ Wout, const float* __restrict__ bout,
    const float* __restrict__ Wc1, const float* __restrict__ bc1,
    const float* __restrict__ Wc2, const float* __restrict__ bc2,
    const float* __restrict__ proj,
    const u16* __restrict__ Kl, const u16* __restrict__ Vl,
    const float* __restrict__ ctx, const float* __restrict__ ksum,
    const float* __restrict__ x0, float* __restrict__ out) {
  int b = blockIdx.x;
  int t = threadIdx.x;
  __shared__ float x0s[64], hn1[64], q[512], buf[288], o512[512];
  __shared__ float dots[2048], pol[4][64], red[4];
  __shared__ float y1[64], hn2[64], gact[256], hfin[64], repS[64], c1s[32];
  const float dn = 0.35355339059327373f;
  const float ratio = 1.0f / sqrtf(266.0f);

  if (t < 64) {  // LN1 at position 0
    float xv = x0[b * 64 + t];
    x0s[t] = xv;
    float mu = wredsum64(xv) * 0.015625f;
    float dv = xv - mu;
    float var = wredsum64(dv * dv) * 0.015625f;
    hn1[t] = dv * rsqrtf(var + 1e-5f) * ln1g[t] + ln1b[t];
  }
  __syncthreads();
  for (int c = t; c < 512; c += 256) {  // q row (rotary at n=0 is identity)
    float s = 0;
    for (int d = 0; d < 64; ++d) s += hn1[d] * Wq[d * 512 + c];
    q[c] = s;
  }
  __syncthreads();

  // global heads
  for (int h = 0; h < 4; ++h) {
    float dq = 0;
    for (int d = 0; d < 64; ++d) {
      float qv = q[h * 64 + d];
      dq += qv * qv;
    }
    dq *= 0.0625f;
    float lmax = -3e38f;
    for (int m = t; m < NBF; m += 256) {
      const float* pp = proj + m * 64;
      float s = 0;
#pragma unroll
      for (int d4 = 0; d4 < 16; ++d4) {
        float4 uu = *reinterpret_cast<const float4*>(pp + d4 * 4);
        s += q[h * 64 + d4 * 4] * uu.x + q[h * 64 + d4 * 4 + 1] * uu.y +
             q[h * 64 + d4 * 4 + 2] * uu.z + q[h * 64 + d4 * 4 + 3] * uu.w;
      }
      float dash = dn * s;
      buf[m] = dash;
      lmax = fmaxf(lmax, dash);
    }
    float mxq = bmax256(lmax, red);
    for (int m = t; m < NBF; m += 256)
      buf[m] = ratio * (expf(buf[m] - dq - mxq) + 1e-4f);
    __syncthreads();
    float part = 0;
    for (int m = t; m < NBF; m += 256) part += buf[m] * ksum[(b * 4 + h) * NBF + m];
    float den = bsum256(part, red);
    {
      int d = t & 63, mg = t >> 6;
      float s = 0;
      for (int m = mg; m < NBF; m += 4)
        s += buf[m] * ctx[(((size_t)(b * 4 + h)) * NBF + m) * 64 + d];
      pol[mg][d] = s;
    }
    __syncthreads();
    if (t < 64) o512[h * 64 + t] = (pol[0][t] + pol[1][t] + pol[2][t] + pol[3][t]) / den;
    __syncthreads();
  }

  // local heads (softmax attention, query row 0 only)
  for (int h = 0; h < 4; ++h) {
    size_t base = (size_t)(b * 4 + h) * NTOK;
    float lmax = -3e38f;
    for (int n1 = t; n1 < NTOK; n1 += 256) {
      const ushort4* kr4 = reinterpret_cast<const ushort4*>(Kl + (base + n1) * 64);
      float s = 0;
#pragma unroll
      for (int d4 = 0; d4 < 16; ++d4) {
        ushort4 uu = kr4[d4];
        s += q[(4 + h) * 64 + d4 * 4] * bf2f(uu.x) +
             q[(4 + h) * 64 + d4 * 4 + 1] * bf2f(uu.y) +
             q[(4 + h) * 64 + d4 * 4 + 2] * bf2f(uu.z) +
             q[(4 + h) * 64 + d4 * 4 + 3] * bf2f(uu.w);
      }
      float dv = s * 0.125f;
      if (ids[b * NTOK + n1] == 0) dv = -1e9f;
      dots[n1] = dv;
      lmax = fmaxf(lmax, dv);
    }
    float mxl = bmax256(lmax, red);
    float ps = 0;
    for (int n1 = t; n1 < NTOK; n1 += 256) {
      float p = expf(dots[n1] - mxl);
      dots[n1] = p;
      ps += p;
    }
    float sden = bsum256(ps, red);
    {
      int d = t & 63, ng = t >> 6;
      float s = 0;
      for (int n1 = ng; n1 < NTOK; n1 += 4)
        s += dots[n1] * bf2f(Vl[(base + n1) * 64 + d]);
      pol[ng][d] = s;
    }
    __syncthreads();
    if (t < 64)
      o512[(4 + h) * 64 + t] = (pol[0][t] + pol[1][t] + pol[2][t] + pol[3][t]) / sden;
    __syncthreads();
  }

  // Wo, residual, FF, final LN, heads
  if (t < 64) {
    float s = 0;
    for (int c = 0; c < 512; ++c) s += o512[c] * Wo[c * 64 + t];
    float yv = x0s[t] + s;
    y1[t] = yv;
    float mu = wredsum64(yv) * 0.015625f;
    float dv = yv - mu;
    float var = wredsum64(dv * dv) * 0.015625f;
    hn2[t] = dv * rsqrtf(var + 1e-5f) * ln2g[t] + ln2b[t];
  }
  __syncthreads();
  {
    float s = b1[t];
    for (int d = 0; d < 64; ++d) s += hn2[d] * W1[d * 256 + t];
    gact[t] = 0.5f * s * (1.f + erff(s * 0.7071067811865475f));  // exact gelu
  }
  __syncthreads();
  if (t < 64) {
    float s = b2[t];
    for (int jj = 0; jj < 256; ++jj) s += gact[jj] * W2[jj * 64 + t];
    float y2 = x0s[t] + s;
    float hm = 0.5f * (y1[t] + y2);
    float mu = wredsum64(hm) * 0.015625f;
    float dv = hm - mu;
    float var = wredsum64(dv * dv) * 0.015625f;
    hfin[t] = dv * rsqrtf(var + 1e-5f) * lnfg[t] + lnfb[t];
  }
  __syncthreads();
  if (t < 64) {
    float s = bout[t];
    for (int d = 0; d < 64; ++d) s += hfin[d] * Wout[d * 64 + t];
    repS[t] = s;
    out[16 + b * 64 + t] = s;  // rep output (f32)
  }
  __syncthreads();
  if (t < 32) {
    float s = bc1[t];
    for (int d = 0; d < 64; ++d) s += repS[d] * Wc1[d * 32 + t];
    c1s[t] = fmaxf(s, 0.f);
  }
  __syncthreads();
  if (t < 2) {
    float s = bc2[t];
    for (int jj = 0; jj < 32; ++jj) s += c1s[jj] * Wc2[jj * 2 + t];
    out[b * 2 + t] = s;  // classifier output (f32)
  }
}

extern "C" void kernel_launch(void* const* d_in, const int* in_sizes, int n_in,
                              void* d_out, int out_size, void* d_ws, size_t ws_size,
                              hipStream_t stream) {
  (void)in_sizes; (void)n_in; (void)out_size; (void)ws_size;
  const int* ids = (const int*)d_in[0];
  const float* tok = (const float*)d_in[1];
  const float* ln1g = (const float*)d_in[2];
  const float* ln1b = (const float*)d_in[3];
  const float* Wq = (const float*)d_in[4];
  const float* Wk = (const float*)d_in[5];
  const float* Wv = (const float*)d_in[6];
  const float* Wo = (const float*)d_in[7];
  const float* ln2g = (const float*)d_in[8];
  const float* ln2b = (const float*)d_in[9];
  const float* W1 = (const float*)d_in[10];
  const float* b1 = (const float*)d_in[11];
  const float* W2 = (const float*)d_in[12];
  const float* b2 = (const float*)d_in[13];
  const float* lnfg = (const float*)d_in[14];
  const float* lnfb = (const float*)d_in[15];
  const float* Wout = (const float*)d_in[16];
  const float* bout = (const float*)d_in[17];
  const float* Wc1 = (const float*)d_in[18];
  const float* bc1 = (const float*)d_in[19];
  const float* Wc2 = (const float*)d_in[20];
  const float* bc2 = (const float*)d_in[21];
  const float* proj = (const float*)d_in[22];

  uint8_t* w = (uint8_t*)d_ws;
  size_t off = 0;
  const size_t big = (size_t)8 * 4 * NTOK * 64 * 2;  // 8.39 MB each
  u16* Kg = (u16*)(w + off); off += big;
  u16* Vg = (u16*)(w + off); off += big;
  u16* Kl = (u16*)(w + off); off += big;
  u16* Vl = (u16*)(w + off); off += big;
  float* diagK = (float*)(w + off); off += (size_t)8 * 4 * NTOK * 4;
  float* ctx = (float*)(w + off); off += (size_t)8 * 4 * NBF * 64 * 4;
  float* ksum = (float*)(w + off); off += (size_t)8 * 4 * NBF * 4;
  unsigned int* gmax = (unsigned int*)(w + off); off += 4;
  float* x0 = (float*)(w + off); off += 64 * 8 * 4;

  // zero accumulators + gmax (contiguous: ctx, ksum, gmax)
  hipMemsetAsync(ctx, 0,
                 (size_t)8 * 4 * NBF * 64 * 4 + (size_t)8 * 4 * NBF * 4 + 4, stream);
  k_prep<<<8 * 512, 64, 0, stream>>>(ids, tok, ln1g, ln1b, Wk, Wv, Kg, Vg, Kl, Vl,
                                     diagK, x0);
  k_max<<<dim3(32, 32), 256, 0, stream>>>(Kg, proj, gmax);
  k_ctx<<<dim3(32, 5, 8), 256, 0, stream>>>(Kg, Vg, diagK, proj, gmax, ctx, ksum);
  k_fin<<<8, 256, 0, stream>>>(ids, ln1g, ln1b, Wq, Wo, ln2g, ln2b, W1, b1, W2, b2,
                               lnfg, lnfb, Wout, bout, Wc1, bc1, Wc2, bc2, proj,
                               Kl, Vl, ctx, ksum, x0, (float*)d_out);
}

// Round 5
// 590.031 us; speedup vs baseline: 2.9207x; 1.9652x over previous
//
#include <hip/hip_runtime.h>
#include <math.h>

#define NTOK 2048
#define NBF 266

typedef unsigned short u16;

__device__ __forceinline__ float bf2f(u16 u) {
  unsigned int x = ((unsigned int)u) << 16;
  return __uint_as_float(x);
}
__device__ __forceinline__ u16 f2bf(float f) {
  unsigned int x = __float_as_uint(f);
  unsigned int r = x + 0x7FFFu + ((x >> 16) & 1u);
  return (u16)(r >> 16);
}
__device__ __forceinline__ float wredsum64(float v) {
  for (int o = 32; o > 0; o >>= 1) v += __shfl_xor(v, o);
  return v;
}
__device__ __forceinline__ float bsum256(float v, float* red) {
  for (int o = 32; o > 0; o >>= 1) v += __shfl_xor(v, o);
  __syncthreads();
  if ((threadIdx.x & 63) == 0) red[threadIdx.x >> 6] = v;
  __syncthreads();
  return red[0] + red[1] + red[2] + red[3];
}
__device__ __forceinline__ float bmax256(float v, float* red) {
  for (int o = 32; o > 0; o >>= 1) v = fmaxf(v, __shfl_xor(v, o));
  __syncthreads();
  if ((threadIdx.x & 63) == 0) red[threadIdx.x >> 6] = v;
  __syncthreads();
  return fmaxf(fmaxf(red[0], red[1]), fmaxf(red[2], red[3]));
}
// inv_freq[i] = 10000^(-i/32) = 2^(-i*log2(1e4)/32), i in [0,32)
#define INVF_C 0.4152410118609190f

// ---------------- prep: x, LN1, K/V all heads, rotary(Kg), diag, Vg mask ----
__global__ __launch_bounds__(64) void k_prep(
    const int* __restrict__ ids, const float* __restrict__ tok_emb,
    const float* __restrict__ ln1g, const float* __restrict__ ln1b,
    const float* __restrict__ Wk, const float* __restrict__ Wv,
    u16* __restrict__ Kg, u16* __restrict__ Vg,
    u16* __restrict__ Kl, u16* __restrict__ Vl,
    float* __restrict__ diagK, float* __restrict__ x0) {
  int blk = blockIdx.x;            // 8 * 512 blocks
  int b = blk >> 9, nt = blk & 511;
  int n0 = nt * 4;
  int t = threadIdx.x;
  __shared__ float hn[4][64];
  int idv[4];
  float g = ln1g[t], bb = ln1b[t];
#pragma unroll
  for (int j = 0; j < 4; ++j) {
    int n = n0 + j;
    int id = ids[b * NTOK + n];
    idv[j] = id;
    float ang = (float)n * exp2f(-INVF_C * (float)(t & 31));
    float pv = (t < 32) ? sinf(ang) : cosf(ang);
    float xv = tok_emb[id * 64 + t] + pv;
    float mu = wredsum64(xv) * 0.015625f;
    float dv = xv - mu;
    float var = wredsum64(dv * dv) * 0.015625f;
    hn[j][t] = dv * rsqrtf(var + 1e-5f) * g + bb;
    if (n == 0) x0[b * 64 + t] = xv;
  }
  __syncthreads();

  float ka[4][8], va[4][8];
#pragma unroll
  for (int j = 0; j < 4; ++j)
#pragma unroll
    for (int i = 0; i < 8; ++i) { ka[j][i] = 0.f; va[j][i] = 0.f; }
  const float* wk = Wk + t * 8;
  const float* wv = Wv + t * 8;
  for (int d2 = 0; d2 < 64; ++d2) {
    float4 k0 = *reinterpret_cast<const float4*>(wk + d2 * 512);
    float4 k1 = *reinterpret_cast<const float4*>(wk + d2 * 512 + 4);
    float4 v0 = *reinterpret_cast<const float4*>(wv + d2 * 512);
    float4 v1 = *reinterpret_cast<const float4*>(wv + d2 * 512 + 4);
#pragma unroll
    for (int j = 0; j < 4; ++j) {
      float hv = hn[j][d2];
      ka[j][0] += hv * k0.x; ka[j][1] += hv * k0.y;
      ka[j][2] += hv * k0.z; ka[j][3] += hv * k0.w;
      ka[j][4] += hv * k1.x; ka[j][5] += hv * k1.y;
      ka[j][6] += hv * k1.z; ka[j][7] += hv * k1.w;
      va[j][0] += hv * v0.x; va[j][1] += hv * v0.y;
      va[j][2] += hv * v0.z; va[j][3] += hv * v0.w;
      va[j][4] += hv * v1.x; va[j][5] += hv * v1.y;
      va[j][6] += hv * v1.z; va[j][7] += hv * v1.w;
    }
  }

  int jh = t >> 3;                // head
  int db = (t & 7) * 8;           // d offset within head
#pragma unroll
  for (int j = 0; j < 4; ++j) {
    int n = n0 + j;
    float maskf = (idv[j] != 0) ? 1.f : 0.f;
    if (jh < 4) {                 // global heads: rotary K, diag, masked Vg
      float kr[8];
#pragma unroll
      for (int p = 0; p < 4; ++p) {
        int q = (db >> 1) + p;
        float ang = (float)n * exp2f(-INVF_C * (float)q);
        float sv = sinf(ang), cv = cosf(ang);
        float e0 = ka[j][2 * p], e1 = ka[j][2 * p + 1];
        kr[2 * p] = e0 * cv - e1 * sv;
        kr[2 * p + 1] = e1 * cv + e0 * sv;
      }
      float dq = 0;
#pragma unroll
      for (int i = 0; i < 8; ++i) dq += kr[i] * kr[i];
      dq += __shfl_xor(dq, 1);
      dq += __shfl_xor(dq, 2);
      dq += __shfl_xor(dq, 4);
      size_t hb = (size_t)(b * 4 + jh) * NTOK + n;
      if ((t & 7) == 0) diagK[hb] = dq * 0.0625f;  // 0.5*dn*dn = 1/16
      size_t base = hb * 64 + db;
      ushort4 s0, s1;
      s0.x = f2bf(kr[0]); s0.y = f2bf(kr[1]); s0.z = f2bf(kr[2]); s0.w = f2bf(kr[3]);
      s1.x = f2bf(kr[4]); s1.y = f2bf(kr[5]); s1.z = f2bf(kr[6]); s1.w = f2bf(kr[7]);
      *reinterpret_cast<ushort4*>(Kg + base) = s0;
      *reinterpret_cast<ushort4*>(Kg + base + 4) = s1;
      ushort4 m0, m1;
      m0.x = f2bf(va[j][0] * maskf); m0.y = f2bf(va[j][1] * maskf);
      m0.z = f2bf(va[j][2] * maskf); m0.w = f2bf(va[j][3] * maskf);
      m1.x = f2bf(va[j][4] * maskf); m1.y = f2bf(va[j][5] * maskf);
      m1.z = f2bf(va[j][6] * maskf); m1.w = f2bf(va[j][7] * maskf);
      *reinterpret_cast<ushort4*>(Vg + base) = m0;
      *reinterpret_cast<ushort4*>(Vg + base + 4) = m1;
    } else {                      // local heads: raw K, raw V
      size_t base = ((size_t)(b * 4 + (jh - 4)) * NTOK + n) * 64 + db;
      ushort4 s0, s1, v0, v1;
      s0.x = f2bf(ka[j][0]); s0.y = f2bf(ka[j][1]);
      s0.z = f2bf(ka[j][2]); s0.w = f2bf(ka[j][3]);
      s1.x = f2bf(ka[j][4]); s1.y = f2bf(ka[j][5]);
      s1.z = f2bf(ka[j][6]); s1.w = f2bf(ka[j][7]);
      v0.x = f2bf(va[j][0]); v0.y = f2bf(va[j][1]);
      v0.z = f2bf(va[j][2]); v0.w = f2bf(va[j][3]);
      v1.x = f2bf(va[j][4]); v1.y = f2bf(va[j][5]);
      v1.z = f2bf(va[j][6]); v1.w = f2bf(va[j][7]);
      *reinterpret_cast<ushort4*>(Kl + base) = s0;
      *reinterpret_cast<ushort4*>(Kl + base + 4) = s1;
      *reinterpret_cast<ushort4*>(Vl + base) = v0;
      *reinterpret_cast<ushort4*>(Vl + base + 4) = v1;
    }
  }
}

// ---------------- global max over dash = dn * Kg @ proj^T --------------------
__global__ __launch_bounds__(256) void k_max(
    const u16* __restrict__ Kg, const float* __restrict__ proj,
    unsigned int* __restrict__ gmax) {
  int bh = blockIdx.x;
  int n0 = blockIdx.y * 64;
  __shared__ float4 kg[1024];  // 64 rows x 16 float4
  __shared__ float red[4];
  size_t base = ((size_t)bh * NTOK + n0) * 64;
  const ushort4* src = reinterpret_cast<const ushort4*>(Kg + base);
  for (int i = threadIdx.x; i < 1024; i += 256) {
    ushort4 u = src[i];
    kg[i] = make_float4(bf2f(u.x), bf2f(u.y), bf2f(u.z), bf2f(u.w));
  }
  __syncthreads();
  float mv = -3e38f;
  for (int m = threadIdx.x; m < NBF; m += 256) {
    float4 pr[16];
    const float4* pp = reinterpret_cast<const float4*>(proj + m * 64);
#pragma unroll
    for (int q = 0; q < 16; ++q) pr[q] = pp[q];
    for (int r = 0; r < 64; ++r) {
      float s = 0;
#pragma unroll
      for (int q = 0; q < 16; ++q) {
        float4 gg = kg[r * 16 + q];
        s += gg.x * pr[q].x + gg.y * pr[q].y + gg.z * pr[q].z + gg.w * pr[q].w;
      }
      mv = fmaxf(mv, s);
    }
  }
  mv *= 0.35355339059327373f;  // dn > 0 so max commutes
  for (int o = 32; o > 0; o >>= 1) mv = fmaxf(mv, __shfl_xor(mv, o));
  if ((threadIdx.x & 63) == 0) red[threadIdx.x >> 6] = mv;
  __syncthreads();
  if (threadIdx.x == 0) {
    float m2 = fmaxf(fmaxf(red[0], red[1]), fmaxf(red[2], red[3]));
    unsigned int b = __float_as_uint(m2);
    unsigned int u = (b & 0x80000000u) ? ~b : (b | 0x80000000u);
    atomicMax(gmax, u);
  }
}

// ---------------- ctx = kp^T @ Vg, ksum = sum_n kp ---------------------------
__global__ __launch_bounds__(256) void k_ctx(
    const u16* __restrict__ Kg, const u16* __restrict__ Vg,
    const float* __restrict__ diagK, const float* __restrict__ proj,
    const unsigned int* __restrict__ gmax,
    float* __restrict__ ctx, float* __restrict__ ksum) {
  int bh = blockIdx.x;
  int m0 = blockIdx.y * 64;
  int ns = blockIdx.z;
  __shared__ float prj[64 * 66];
  __shared__ float kg4[4 * 64], vg4[4 * 64], kp4[4 * 64], dg4[4];
  int t = threadIdx.x;
  for (int idx = t; idx < 4096; idx += 256) {
    int r = idx >> 6, d = idx & 63;
    int m = m0 + r;
    prj[r * 66 + d] = (m < NBF) ? proj[m * 64 + d] : 0.f;
  }
  unsigned int u = *gmax;
  unsigned int bb = (u & 0x80000000u) ? (u & 0x7FFFFFFFu) : ~u;
  float mx = __uint_as_float(bb);
  const float dn = 0.35355339059327373f;
  const float ratio = 1.0f / sqrtf(266.0f);
  float acc[16];
#pragma unroll
  for (int i = 0; i < 16; ++i) acc[i] = 0.f;
  float ks = 0.f;
  int ml = t & 63, wg = t >> 6;
  int n0 = ns * 256;
  for (int nn = n0; nn < n0 + 256; nn += 4) {
    __syncthreads();
    {
      int r = t >> 6, d = t & 63;
      size_t gi = ((size_t)bh * NTOK + nn + r) * 64 + d;
      kg4[t] = bf2f(Kg[gi]);
      vg4[t] = bf2f(Vg[gi]);
      if (t < 4) dg4[t] = diagK[(size_t)bh * NTOK + nn + t];
    }
    __syncthreads();
    {
      float s = 0;
      const float2* kk = reinterpret_cast<const float2*>(&kg4[wg * 64]);
      const float2* pp = reinterpret_cast<const float2*>(&prj[ml * 66]);
#pragma unroll
      for (int d2 = 0; d2 < 32; ++d2) {
        float2 a = kk[d2], p = pp[d2];
        s += a.x * p.x + a.y * p.y;
      }
      float dash = dn * s;
      int m = m0 + ml;
      kp4[wg * 64 + ml] = (m < NBF) ? ratio * (expf(dash - dg4[wg] - mx) + 1e-4f) : 0.f;
    }
    __syncthreads();
#pragma unroll
    for (int r = 0; r < 4; ++r) {
      float kv = kp4[r * 64 + ml];
      if (wg == 0) ks += kv;
      const float4* vrow = reinterpret_cast<const float4*>(&vg4[r * 64 + wg * 16]);
#pragma unroll
      for (int dd = 0; dd < 4; ++dd) {
        float4 vv = vrow[dd];
        acc[dd * 4 + 0] += kv * vv.x;
        acc[dd * 4 + 1] += kv * vv.y;
        acc[dd * 4 + 2] += kv * vv.z;
        acc[dd * 4 + 3] += kv * vv.w;
      }
    }
  }
  int m = m0 + ml;
  if (m < NBF) {
    float* cp = &ctx[((size_t)bh * NBF + m) * 64 + wg * 16];
#pragma unroll
    for (int dd = 0; dd < 16; ++dd) atomicAdd(&cp[dd], acc[dd]);
    if (wg == 0) atomicAdd(&ksum[(size_t)bh * NBF + m], ks);
  }
}

// ---------------- attention row 0, one block per (b, head) ------------------
__global__ __launch_bounds__(256) void k_att(
    const int* __restrict__ ids,
    const float* __restrict__ ln1g, const float* __restrict__ ln1b,
    const float* __restrict__ Wq, const float* __restrict__ proj,
    const u16* __restrict__ Kl, const u16* __restrict__ Vl,
    const float* __restrict__ ctx, const float* __restrict__ ksum,
    const float* __restrict__ x0, float* __restrict__ att) {
  int b = blockIdx.x, h = blockIdx.y;
  int t = threadIdx.x;
  int lane = t & 63, wg = t >> 6;
  __shared__ float hn1[64], qh[64], qpart[4][64], red[4], pol[4][64];
  __shared__ float buf[272];
  __shared__ float dots[2048];
  __shared__ u16 vst[512 * 64];
  const float dn = 0.35355339059327373f;
  const float ratio = 1.0f / sqrtf(266.0f);

  if (t < 64) {  // LN1 at position 0 (one wave)
    float xv = x0[b * 64 + t];
    float mu = wredsum64(xv) * 0.015625f;
    float dv = xv - mu;
    float var = wredsum64(dv * dv) * 0.015625f;
    hn1[t] = dv * rsqrtf(var + 1e-5f) * ln1g[t] + ln1b[t];
  }
  __syncthreads();
  {  // q head-slice: out j=lane, partials over d in [wg*16, wg*16+16)
    float p = 0;
#pragma unroll
    for (int dd = 0; dd < 16; ++dd)
      p += hn1[wg * 16 + dd] * Wq[(wg * 16 + dd) * 512 + h * 64 + lane];
    qpart[wg][lane] = p;
  }
  __syncthreads();
  if (t < 64) qh[t] = qpart[0][t] + qpart[1][t] + qpart[2][t] + qpart[3][t];
  __syncthreads();

  if (h < 4) {
    // ---- global (Performer) head ----
    int bh = b * 4 + h;
    float dq = 0;
#pragma unroll
    for (int d = 0; d < 64; ++d) dq += qh[d] * qh[d];
    dq *= 0.0625f;
    float lmax = -3e38f;
#pragma unroll
    for (int pass = 0; pass < 2; ++pass) {
      int m = t + pass * 256;
      if (m < NBF) {
        const float4* pp = reinterpret_cast<const float4*>(proj + m * 64);
        float s = 0;
#pragma unroll
        for (int q4 = 0; q4 < 16; ++q4) {
          float4 uu = pp[q4];
          s += qh[q4 * 4] * uu.x + qh[q4 * 4 + 1] * uu.y +
               qh[q4 * 4 + 2] * uu.z + qh[q4 * 4 + 3] * uu.w;
        }
        float dash = dn * s;
        buf[m] = dash;
        lmax = fmaxf(lmax, dash);
      }
    }
    float mxq = bmax256(lmax, red);
    float part = 0;
#pragma unroll
    for (int pass = 0; pass < 2; ++pass) {
      int m = t + pass * 256;
      if (m < NBF) {
        float qp = ratio * (expf(buf[m] - dq - mxq) + 1e-4f);
        buf[m] = qp;
        part += qp * ksum[(size_t)bh * NBF + m];
      }
    }
    float den = bsum256(part, red);
    __syncthreads();
    {
      float s = 0;
      for (int m = wg; m < NBF; m += 4)
        s += buf[m] * ctx[((size_t)bh * NBF + m) * 64 + lane];
      pol[wg][lane] = s;
    }
    __syncthreads();
    if (t < 64)
      att[b * 512 + h * 64 + t] =
          (pol[0][t] + pol[1][t] + pol[2][t] + pol[3][t]) / den;
  } else {
    // ---- local (softmax) head ----
    int hl = h - 4;
    size_t base = (size_t)(b * 4 + hl) * NTOK;
    float lmax = -3e38f;
#pragma unroll
    for (int i = 0; i < 8; ++i) {
      int n1 = t + i * 256;
      const ushort4* kr4 = reinterpret_cast<const ushort4*>(Kl + (base + n1) * 64);
      float s = 0;
#pragma unroll
      for (int d4 = 0; d4 < 16; ++d4) {
        ushort4 uu = kr4[d4];
        s += qh[d4 * 4] * bf2f(uu.x) + qh[d4 * 4 + 1] * bf2f(uu.y) +
             qh[d4 * 4 + 2] * bf2f(uu.z) + qh[d4 * 4 + 3] * bf2f(uu.w);
      }
      float dv = s * 0.125f;
      if (ids[b * NTOK + n1] == 0) dv = -1e9f;
      dots[n1] = dv;
      lmax = fmaxf(lmax, dv);
    }
    float mxl = bmax256(lmax, red);
    float ps = 0;
#pragma unroll
    for (int i = 0; i < 8; ++i) {
      int n1 = t + i * 256;
      float p = expf(dots[n1] - mxl);
      dots[n1] = p;
      ps += p;
    }
    float sden = bsum256(ps, red);
    // PV via LDS-staged V chunks (512 rows each)
    float acc = 0;
    for (int c = 0; c < 4; ++c) {
      __syncthreads();
      const ushort4* src = reinterpret_cast<const ushort4*>(Vl + (base + c * 512) * 64);
      ushort4* dst = reinterpret_cast<ushort4*>(vst);
#pragma unroll
      for (int i = 0; i < 32; ++i) dst[t + i * 256] = src[t + i * 256];
      __syncthreads();
      int r0 = wg * 128;
#pragma unroll 8
      for (int r = 0; r < 128; ++r)
        acc += dots[c * 512 + r0 + r] * bf2f(vst[(r0 + r) * 64 + lane]);
    }
    __syncthreads();
    pol[wg][lane] = acc;
    __syncthreads();
    if (t < 64)
      att[b * 512 + h * 64 + t] =
          (pol[0][t] + pol[1][t] + pol[2][t] + pol[3][t]) / sden;
  }
}

// ---------------- tail at position 0: Wo, FF, final LN, heads ----------------
__global__ __launch_bounds__(256) void k_fin2(
    const float* __restrict__ ln2g, const float* __restrict__ ln2b,
    const float* __restrict__ Wo,
    const float* __restrict__ W1, const float* __restrict__ b1,
    const float* __restrict__ W2, const float* __restrict__ b2,
    const float* __restrict__ lnfg, const float* __restrict__ lnfb,
    const float* __restrict__ Wout, const float* __restrict__ bout,
    const float* __restrict__ Wc1, const float* __restrict__ bc1,
    const float* __restrict__ Wc2, const float* __restrict__ bc2,
    const float* __restrict__ x0, const float* __restrict__ att,
    float* __restrict__ out) {
  int b = blockIdx.x;
  int t = threadIdx.x;
  int lane = t & 63, wg = t >> 6;
  __shared__ float o512s[512], x0s[64], part[4][64];
  __shared__ float y1[64], hn2[64], gact[256], hfin[64], repS[64], c1s[32];
  o512s[t] = att[b * 512 + t];
  o512s[t + 256] = att[b * 512 + t + 256];
  if (t < 64) x0s[t] = x0[b * 64 + t];
  __syncthreads();
  {  // Wo GEMV: out d=lane, partial over c in [wg*128, +128)
    float s = 0;
#pragma unroll 4
    for (int c = wg * 128; c < wg * 128 + 128; ++c) s += o512s[c] * Wo[c * 64 + lane];
    part[wg][lane] = s;
  }
  __syncthreads();
  if (t < 64) {
    float yv = x0s[t] + part[0][t] + part[1][t] + part[2][t] + part[3][t];
    y1[t] = yv;
    float mu = wredsum64(yv) * 0.015625f;
    float dv = yv - mu;
    float var = wredsum64(dv * dv) * 0.015625f;
    hn2[t] = dv * rsqrtf(var + 1e-5f) * ln2g[t] + ln2b[t];
  }
  __syncthreads();
  {  // W1 + gelu (256 outputs, one per thread)
    float s = b1[t];
#pragma unroll 4
    for (int d = 0; d < 64; ++d) s += hn2[d] * W1[d * 256 + t];
    gact[t] = 0.5f * s * (1.f + erff(s * 0.7071067811865475f));
  }
  __syncthreads();
  {  // W2 GEMV: out d=lane, partial over j in [wg*64, +64)
    float s = 0;
#pragma unroll 4
    for (int j = wg * 64; j < wg * 64 + 64; ++j) s += gact[j] * W2[j * 64 + lane];
    part[wg][lane] = s;
  }
  __syncthreads();
  if (t < 64) {
    float y2 = x0s[t] + b2[t] + part[0][t] + part[1][t] + part[2][t] + part[3][t];
    float hm = 0.5f * (y1[t] + y2);
    float mu = wredsum64(hm) * 0.015625f;
    float dv = hm - mu;
    float var = wredsum64(dv * dv) * 0.015625f;
    hfin[t] = dv * rsqrtf(var + 1e-5f) * lnfg[t] + lnfb[t];
  }
  __syncthreads();
  {  // Wout GEMV: out j=lane, partial over d in [wg*16, +16)
    float s = 0;
#pragma unroll
    for (int dd = 0; dd < 16; ++dd)
      s += hfin[wg * 16 + dd] * Wout[(wg * 16 + dd) * 64 + lane];
    part[wg][lane] = s;
  }
  __syncthreads();
  if (t < 64) {
    float s = bout[t] + part[0][t] + part[1][t] + part[2][t] + part[3][t];
    repS[t] = s;
    out[16 + b * 64 + t] = s;  // rep output
  }
  __syncthreads();
  if (t < 32) {
    float s = bc1[t];
#pragma unroll 4
    for (int d = 0; d < 64; ++d) s += repS[d] * Wc1[d * 32 + t];
    c1s[t] = fmaxf(s, 0.f);
  }
  __syncthreads();
  if (t < 2) {
    float s = bc2[t];
#pragma unroll
    for (int jj = 0; jj < 32; ++jj) s += c1s[jj] * Wc2[jj * 2 + t];
    out[b * 2 + t] = s;  // classifier output
  }
}

extern "C" void kernel_launch(void* const* d_in, const int* in_sizes, int n_in,
                              void* d_out, int out_size, void* d_ws, size_t ws_size,
                              hipStream_t stream) {
  (void)in_sizes; (void)n_in; (void)out_size; (void)ws_size;
  const int* ids = (const int*)d_in[0];
  const float* tok = (const float*)d_in[1];
  const float* ln1g = (const float*)d_in[2];
  const float* ln1b = (const float*)d_in[3];
  const float* Wq = (const float*)d_in[4];
  const float* Wk = (const float*)d_in[5];
  const float* Wv = (const float*)d_in[6];
  const float* Wo = (const float*)d_in[7];
  const float* ln2g = (const float*)d_in[8];
  const float* ln2b = (const float*)d_in[9];
  const float* W1 = (const float*)d_in[10];
  const float* b1 = (const float*)d_in[11];
  const float* W2 = (const float*)d_in[12];
  const float* b2 = (const float*)d_in[13];
  const float* lnfg = (const float*)d_in[14];
  const float* lnfb = (const float*)d_in[15];
  const float* Wout = (const float*)d_in[16];
  const float* bout = (const float*)d_in[17];
  const float* Wc1 = (const float*)d_in[18];
  const float* bc1 = (const float*)d_in[19];
  const float* Wc2 = (const float*)d_in[20];
  const float* bc2 = (const float*)d_in[21];
  const float* proj = (const float*)d_in[22];

  uint8_t* w = (uint8_t*)d_ws;
  size_t off = 0;
  const size_t big = (size_t)8 * 4 * NTOK * 64 * 2;  // 8.39 MB each
  u16* Kg = (u16*)(w + off); off += big;
  u16* Vg = (u16*)(w + off); off += big;
  u16* Kl = (u16*)(w + off); off += big;
  u16* Vl = (u16*)(w + off); off += big;
  float* diagK = (float*)(w + off); off += (size_t)8 * 4 * NTOK * 4;
  float* ctx = (float*)(w + off); off += (size_t)8 * 4 * NBF * 64 * 4;
  float* ksum = (float*)(w + off); off += (size_t)8 * 4 * NBF * 4;
  unsigned int* gmax = (unsigned int*)(w + off); off += 4;
  float* x0 = (float*)(w + off); off += 64 * 8 * 4;
  float* att = (float*)(w + off); off += (size_t)8 * 512 * 4;

  // zero accumulators + gmax (contiguous: ctx, ksum, gmax)
  hipMemsetAsync(ctx, 0,
                 (size_t)8 * 4 * NBF * 64 * 4 + (size_t)8 * 4 * NBF * 4 + 4, stream);
  k_prep<<<8 * 512, 64, 0, stream>>>(ids, tok, ln1g, ln1b, Wk, Wv, Kg, Vg, Kl, Vl,
                                     diagK, x0);
  k_max<<<dim3(32, 32), 256, 0, stream>>>(Kg, proj, gmax);
  k_ctx<<<dim3(32, 5, 8), 256, 0, stream>>>(Kg, Vg, diagK, proj, gmax, ctx, ksum);
  k_att<<<dim3(8, 8), 256, 0, stream>>>(ids, ln1g, ln1b, Wq, proj, Kl, Vl, ctx,
                                        ksum, x0, att);
  k_fin2<<<8, 256, 0, stream>>>(ln2g, ln2b, Wo, W1, b1, W2, b2, lnfg, lnfb, Wout,
                                bout, Wc1, bc1, Wc2, bc2, x0, att, (float*)d_out);
}

// Round 6
// 171.474 us; speedup vs baseline: 10.0500x; 3.4409x over previous
//
#include <hip/hip_runtime.h>
#include <math.h>

#define NTOK 2048
#define NBF 266
#define MPAD 272

typedef unsigned short u16;
typedef __attribute__((ext_vector_type(8))) short short8;
typedef __attribute__((ext_vector_type(4))) float f32x4;

__device__ __forceinline__ float bf2f(u16 u) {
  unsigned int x = ((unsigned int)u) << 16;
  return __uint_as_float(x);
}
__device__ __forceinline__ u16 f2bf(float f) {
  unsigned int x = __float_as_uint(f);
  unsigned int r = x + 0x7FFFu + ((x >> 16) & 1u);
  return (u16)(r >> 16);
}
__device__ __forceinline__ float wredsum64(float v) {
  for (int o = 32; o > 0; o >>= 1) v += __shfl_xor(v, o);
  return v;
}
__device__ __forceinline__ float bsum256(float v, float* red) {
  for (int o = 32; o > 0; o >>= 1) v += __shfl_xor(v, o);
  __syncthreads();
  if ((threadIdx.x & 63) == 0) red[threadIdx.x >> 6] = v;
  __syncthreads();
  return red[0] + red[1] + red[2] + red[3];
}
__device__ __forceinline__ float bmax256(float v, float* red) {
  for (int o = 32; o > 0; o >>= 1) v = fmaxf(v, __shfl_xor(v, o));
  __syncthreads();
  if ((threadIdx.x & 63) == 0) red[threadIdx.x >> 6] = v;
  __syncthreads();
  return fmaxf(fmaxf(red[0], red[1]), fmaxf(red[2], red[3]));
}
#define INVF_C 0.4152410118609190f

// ---------------- prep: x, LN1, K/V all heads, rotary(Kg), diag, Vg mask ----
__global__ __launch_bounds__(64) void k_prep(
    const int* __restrict__ ids, const float* __restrict__ tok_emb,
    const float* __restrict__ ln1g, const float* __restrict__ ln1b,
    const float* __restrict__ Wk, const float* __restrict__ Wv,
    u16* __restrict__ Kg, u16* __restrict__ Vg,
    u16* __restrict__ Kl, u16* __restrict__ Vl,
    float* __restrict__ diagK, float* __restrict__ x0) {
  int blk = blockIdx.x;            // 8 * 512 blocks
  int b = blk >> 9, nt = blk & 511;
  int n0 = nt * 4;
  int t = threadIdx.x;
  __shared__ float hn[4][64];
  int idv[4];
  float g = ln1g[t], bb = ln1b[t];
#pragma unroll
  for (int j = 0; j < 4; ++j) {
    int n = n0 + j;
    int id = ids[b * NTOK + n];
    idv[j] = id;
    float ang = (float)n * exp2f(-INVF_C * (float)(t & 31));
    float pv = (t < 32) ? sinf(ang) : cosf(ang);
    float xv = tok_emb[id * 64 + t] + pv;
    float mu = wredsum64(xv) * 0.015625f;
    float dv = xv - mu;
    float var = wredsum64(dv * dv) * 0.015625f;
    hn[j][t] = dv * rsqrtf(var + 1e-5f) * g + bb;
    if (n == 0) x0[b * 64 + t] = xv;
  }
  __syncthreads();

  float ka[4][8], va[4][8];
#pragma unroll
  for (int j = 0; j < 4; ++j)
#pragma unroll
    for (int i = 0; i < 8; ++i) { ka[j][i] = 0.f; va[j][i] = 0.f; }
  const float* wk = Wk + t * 8;
  const float* wv = Wv + t * 8;
  for (int d2 = 0; d2 < 64; ++d2) {
    float4 k0 = *reinterpret_cast<const float4*>(wk + d2 * 512);
    float4 k1 = *reinterpret_cast<const float4*>(wk + d2 * 512 + 4);
    float4 v0 = *reinterpret_cast<const float4*>(wv + d2 * 512);
    float4 v1 = *reinterpret_cast<const float4*>(wv + d2 * 512 + 4);
#pragma unroll
    for (int j = 0; j < 4; ++j) {
      float hv = hn[j][d2];
      ka[j][0] += hv * k0.x; ka[j][1] += hv * k0.y;
      ka[j][2] += hv * k0.z; ka[j][3] += hv * k0.w;
      ka[j][4] += hv * k1.x; ka[j][5] += hv * k1.y;
      ka[j][6] += hv * k1.z; ka[j][7] += hv * k1.w;
      va[j][0] += hv * v0.x; va[j][1] += hv * v0.y;
      va[j][2] += hv * v0.z; va[j][3] += hv * v0.w;
      va[j][4] += hv * v1.x; va[j][5] += hv * v1.y;
      va[j][6] += hv * v1.z; va[j][7] += hv * v1.w;
    }
  }

  int jh = t >> 3;                // head
  int db = (t & 7) * 8;           // d offset within head
#pragma unroll
  for (int j = 0; j < 4; ++j) {
    int n = n0 + j;
    float maskf = (idv[j] != 0) ? 1.f : 0.f;
    if (jh < 4) {                 // global heads: rotary K, diag, masked Vg
      float kr[8];
#pragma unroll
      for (int p = 0; p < 4; ++p) {
        int q = (db >> 1) + p;
        float ang = (float)n * exp2f(-INVF_C * (float)q);
        float sv = sinf(ang), cv = cosf(ang);
        float e0 = ka[j][2 * p], e1 = ka[j][2 * p + 1];
        kr[2 * p] = e0 * cv - e1 * sv;
        kr[2 * p + 1] = e1 * cv + e0 * sv;
      }
      float dq = 0;
#pragma unroll
      for (int i = 0; i < 8; ++i) dq += kr[i] * kr[i];
      dq += __shfl_xor(dq, 1);
      dq += __shfl_xor(dq, 2);
      dq += __shfl_xor(dq, 4);
      size_t hb = (size_t)(b * 4 + jh) * NTOK + n;
      if ((t & 7) == 0) diagK[hb] = dq * 0.0625f;  // 0.5*dn*dn = 1/16
      size_t base = hb * 64 + db;
      ushort4 s0, s1;
      s0.x = f2bf(kr[0]); s0.y = f2bf(kr[1]); s0.z = f2bf(kr[2]); s0.w = f2bf(kr[3]);
      s1.x = f2bf(kr[4]); s1.y = f2bf(kr[5]); s1.z = f2bf(kr[6]); s1.w = f2bf(kr[7]);
      *reinterpret_cast<ushort4*>(Kg + base) = s0;
      *reinterpret_cast<ushort4*>(Kg + base + 4) = s1;
      ushort4 m0, m1;
      m0.x = f2bf(va[j][0] * maskf); m0.y = f2bf(va[j][1] * maskf);
      m0.z = f2bf(va[j][2] * maskf); m0.w = f2bf(va[j][3] * maskf);
      m1.x = f2bf(va[j][4] * maskf); m1.y = f2bf(va[j][5] * maskf);
      m1.z = f2bf(va[j][6] * maskf); m1.w = f2bf(va[j][7] * maskf);
      *reinterpret_cast<ushort4*>(Vg + base) = m0;
      *reinterpret_cast<ushort4*>(Vg + base + 4) = m1;
    } else {                      // local heads: raw K, raw V
      size_t base = ((size_t)(b * 4 + (jh - 4)) * NTOK + n) * 64 + db;
      ushort4 s0, s1, v0, v1;
      s0.x = f2bf(ka[j][0]); s0.y = f2bf(ka[j][1]);
      s0.z = f2bf(ka[j][2]); s0.w = f2bf(ka[j][3]);
      s1.x = f2bf(ka[j][4]); s1.y = f2bf(ka[j][5]);
      s1.z = f2bf(ka[j][6]); s1.w = f2bf(ka[j][7]);
      v0.x = f2bf(va[j][0]); v0.y = f2bf(va[j][1]);
      v0.z = f2bf(va[j][2]); v0.w = f2bf(va[j][3]);
      v1.x = f2bf(va[j][4]); v1.y = f2bf(va[j][5]);
      v1.z = f2bf(va[j][6]); v1.w = f2bf(va[j][7]);
      *reinterpret_cast<ushort4*>(Kl + base) = s0;
      *reinterpret_cast<ushort4*>(Kl + base + 4) = s1;
      *reinterpret_cast<ushort4*>(Vl + base) = v0;
      *reinterpret_cast<ushort4*>(Vl + base + 4) = v1;
    }
  }
}

// ---- helper: stage proj (f32) into swizzled bf16 LDS [MPAD][64] ------------
__device__ __forceinline__ void stage_prj(const float* __restrict__ proj,
                                          u16* prjbf, int t) {
  for (int c = t; c < MPAD * 8; c += 256) {   // 16B chunks
    int m = c >> 3, k0 = (c & 7) * 8;
    int e = (m * 64 + k0) ^ ((m & 7) << 3);
    uint4 pk;
    if (m < NBF) {
      const float4* ps = reinterpret_cast<const float4*>(proj + m * 64 + k0);
      float4 p0 = ps[0], p1 = ps[1];
      pk.x = (unsigned)f2bf(p0.x) | ((unsigned)f2bf(p0.y) << 16);
      pk.y = (unsigned)f2bf(p0.z) | ((unsigned)f2bf(p0.w) << 16);
      pk.z = (unsigned)f2bf(p1.x) | ((unsigned)f2bf(p1.y) << 16);
      pk.w = (unsigned)f2bf(p1.z) | ((unsigned)f2bf(p1.w) << 16);
    } else {
      pk.x = pk.y = pk.z = pk.w = 0u;
    }
    *reinterpret_cast<uint4*>(&prjbf[e]) = pk;
  }
}

// ---------------- global max over dash = dn * Kg @ proj^T (MFMA) ------------
__global__ __launch_bounds__(256) void k_max(
    const u16* __restrict__ Kg, const float* __restrict__ proj,
    unsigned int* __restrict__ gmax) {
  int bh = blockIdx.x, ns = blockIdx.y;
  int t = threadIdx.x, lane = t & 63, w = t >> 6;
  __shared__ __align__(16) u16 prjbf[MPAD * 64];
  __shared__ __align__(16) u16 kbf[64 * 64];
  __shared__ float red[4];
  stage_prj(proj, prjbf, t);
  float mv = -3e38f;
  int ko = (lane >> 4) * 8;
  for (int c4 = 0; c4 < 4; ++c4) {
    int nb = ns * 256 + c4 * 64;
    __syncthreads();   // protect kbf from previous iteration's readers
    for (int p = 0; p < 2; ++p) {
      int idx = t + p * 256;
      int n = idx >> 3, k0 = (idx & 7) * 8;
      uint4 src = *reinterpret_cast<const uint4*>(
          Kg + ((size_t)bh * NTOK + nb + n) * 64 + k0);
      *reinterpret_cast<uint4*>(&kbf[(n * 64 + k0) ^ ((n & 7) << 3)]) = src;
    }
    __syncthreads();
    int nl = w * 16 + (lane & 15);
    short8 a0 = *reinterpret_cast<const short8*>(&kbf[(nl * 64 + ko) ^ ((nl & 7) << 3)]);
    short8 a1 = *reinterpret_cast<const short8*>(&kbf[(nl * 64 + ko + 32) ^ ((nl & 7) << 3)]);
#pragma unroll
    for (int mt = 0; mt < 17; ++mt) {
      int m = mt * 16 + (lane & 15);
      short8 b0 = *reinterpret_cast<const short8*>(&prjbf[(m * 64 + ko) ^ ((m & 7) << 3)]);
      short8 b1 = *reinterpret_cast<const short8*>(&prjbf[(m * 64 + ko + 32) ^ ((m & 7) << 3)]);
      f32x4 d = {0.f, 0.f, 0.f, 0.f};
      d = __builtin_amdgcn_mfma_f32_16x16x32_bf16(a0, b0, d, 0, 0, 0);
      d = __builtin_amdgcn_mfma_f32_16x16x32_bf16(a1, b1, d, 0, 0, 0);
      if (m < NBF) {
        mv = fmaxf(mv, fmaxf(fmaxf(d[0], d[1]), fmaxf(d[2], d[3])));
      }
    }
  }
  mv *= 0.35355339059327373f;  // dn > 0: max commutes
  for (int o = 32; o > 0; o >>= 1) mv = fmaxf(mv, __shfl_xor(mv, o));
  __syncthreads();
  if (lane == 0) red[w] = mv;
  __syncthreads();
  if (t == 0) {
    float m2 = fmaxf(fmaxf(red[0], red[1]), fmaxf(red[2], red[3]));
    unsigned int b = __float_as_uint(m2);
    unsigned int u = (b & 0x80000000u) ? ~b : (b | 0x80000000u);
    atomicMax(gmax, u);
  }
}

// ---------------- ctx = kp^T @ Vg, ksum = sum_n kp (MFMA) -------------------
__global__ __launch_bounds__(256) void k_ctx(
    const u16* __restrict__ Kg, const u16* __restrict__ Vg,
    const float* __restrict__ diagK, const float* __restrict__ proj,
    const unsigned int* __restrict__ gmax,
    float* __restrict__ ctx, float* __restrict__ ksum) {
  int bh = blockIdx.x, ns = blockIdx.y;
  int t = threadIdx.x, lane = t & 63, w = t >> 6;
  __shared__ __align__(16) u16 prjbf[MPAD * 64];
  __shared__ __align__(16) u16 kpT[MPAD * 64];
  __shared__ __align__(16) u16 kbf[64 * 64];
  __shared__ __align__(16) u16 vbT[64 * 64];
  __shared__ float dg[64];
  __shared__ float ksl[MPAD];
  stage_prj(proj, prjbf, t);
  if (t < MPAD - 256) ksl[256 + t] = 0.f;
  ksl[t] = 0.f;
  unsigned int u = *gmax;
  unsigned int bb = (u & 0x80000000u) ? (u & 0x7FFFFFFFu) : ~u;
  float mx = __uint_as_float(bb);
  const float dn = 0.35355339059327373f;
  const float ratio = 1.0f / sqrtf(266.0f);
  int ko = (lane >> 4) * 8;
  f32x4 acc[17];
#pragma unroll
  for (int i = 0; i < 17; ++i) acc[i] = (f32x4){0.f, 0.f, 0.f, 0.f};

  for (int c4 = 0; c4 < 4; ++c4) {
    int nb = ns * 256 + c4 * 64;
    // stage K (linear swizzled copy) + V transposed + diag
    for (int p = 0; p < 2; ++p) {
      int idx = t + p * 256;
      int n = idx >> 3, k0 = (idx & 7) * 8;
      uint4 src = *reinterpret_cast<const uint4*>(
          Kg + ((size_t)bh * NTOK + nb + n) * 64 + k0);
      *reinterpret_cast<uint4*>(&kbf[(n * 64 + k0) ^ ((n & 7) << 3)]) = src;
      uint4 vv = *reinterpret_cast<const uint4*>(
          Vg + ((size_t)bh * NTOK + nb + n) * 64 + k0);
      u16 pv[8];
      *reinterpret_cast<uint4*>(pv) = vv;
#pragma unroll
      for (int i = 0; i < 8; ++i) {
        int d = k0 + i;
        vbT[(d * 64 + n) ^ ((d & 7) << 3)] = pv[i];
      }
    }
    if (t < 64) dg[t] = diagK[(size_t)bh * NTOK + nb + t];
    __syncthreads();
    // GEMM1: dash = K @ prj^T ; kp = ratio*(exp(dn*dash - diag - mx)+eps)
    {
      int nl = w * 16 + (lane & 15);
      short8 a0 = *reinterpret_cast<const short8*>(&kbf[(nl * 64 + ko) ^ ((nl & 7) << 3)]);
      short8 a1 = *reinterpret_cast<const short8*>(&kbf[(nl * 64 + ko + 32) ^ ((nl & 7) << 3)]);
      float dgv[4];
#pragma unroll
      for (int r = 0; r < 4; ++r) dgv[r] = dg[w * 16 + (lane >> 4) * 4 + r];
      int n0 = w * 16 + (lane >> 4) * 4;
#pragma unroll
      for (int mt = 0; mt < 17; ++mt) {
        int m = mt * 16 + (lane & 15);
        short8 b0 = *reinterpret_cast<const short8*>(&prjbf[(m * 64 + ko) ^ ((m & 7) << 3)]);
        short8 b1 = *reinterpret_cast<const short8*>(&prjbf[(m * 64 + ko + 32) ^ ((m & 7) << 3)]);
        f32x4 d = {0.f, 0.f, 0.f, 0.f};
        d = __builtin_amdgcn_mfma_f32_16x16x32_bf16(a0, b0, d, 0, 0, 0);
        d = __builtin_amdgcn_mfma_f32_16x16x32_bf16(a1, b1, d, 0, 0, 0);
        float kp0 = ratio * (expf(dn * d[0] - dgv[0] - mx) + 1e-4f);
        float kp1 = ratio * (expf(dn * d[1] - dgv[1] - mx) + 1e-4f);
        float kp2 = ratio * (expf(dn * d[2] - dgv[2] - mx) + 1e-4f);
        float kp3 = ratio * (expf(dn * d[3] - dgv[3] - mx) + 1e-4f);
        ushort4 pkk;
        pkk.x = f2bf(kp0); pkk.y = f2bf(kp1); pkk.z = f2bf(kp2); pkk.w = f2bf(kp3);
        *reinterpret_cast<ushort4*>(&kpT[(m * 64 + n0) ^ ((m & 7) << 3)]) = pkk;
        float ksp = kp0 + kp1 + kp2 + kp3;
        ksp += __shfl_xor(ksp, 16);
        ksp += __shfl_xor(ksp, 32);
        if (lane < 16) atomicAdd(&ksl[mt * 16 + lane], ksp);
      }
    }
    __syncthreads();
    // GEMM2: ctx[m][d] += kpT[m][n] * V^T[d][n]
    {
      int dcol = w * 16 + (lane & 15);
      short8 vb0 = *reinterpret_cast<const short8*>(&vbT[(dcol * 64 + ko) ^ ((dcol & 7) << 3)]);
      short8 vb1 = *reinterpret_cast<const short8*>(&vbT[(dcol * 64 + ko + 32) ^ ((dcol & 7) << 3)]);
#pragma unroll
      for (int mt = 0; mt < 17; ++mt) {
        int m = mt * 16 + (lane & 15);
        short8 a0 = *reinterpret_cast<const short8*>(&kpT[(m * 64 + ko) ^ ((m & 7) << 3)]);
        short8 a1 = *reinterpret_cast<const short8*>(&kpT[(m * 64 + ko + 32) ^ ((m & 7) << 3)]);
        acc[mt] = __builtin_amdgcn_mfma_f32_16x16x32_bf16(a0, vb0, acc[mt], 0, 0, 0);
        acc[mt] = __builtin_amdgcn_mfma_f32_16x16x32_bf16(a1, vb1, acc[mt], 0, 0, 0);
      }
    }
    __syncthreads();  // before next chunk overwrites kbf/vbT/kpT
  }
  // drain ctx accumulators
  int dcol = w * 16 + (lane & 15);
#pragma unroll
  for (int mt = 0; mt < 17; ++mt) {
#pragma unroll
    for (int r = 0; r < 4; ++r) {
      int m = mt * 16 + (lane >> 4) * 4 + r;
      if (m < NBF)
        atomicAdd(&ctx[((size_t)bh * NBF + m) * 64 + dcol], acc[mt][r]);
    }
  }
  __syncthreads();
  for (int c = t; c < NBF; c += 256)
    atomicAdd(&ksum[(size_t)bh * NBF + c], ksl[c]);
}

// ---------------- attention row 0, one block per (b, head) ------------------
__global__ __launch_bounds__(256) void k_att(
    const int* __restrict__ ids,
    const float* __restrict__ ln1g, const float* __restrict__ ln1b,
    const float* __restrict__ Wq, const float* __restrict__ proj,
    const u16* __restrict__ Kl, const u16* __restrict__ Vl,
    const float* __restrict__ ctx, const float* __restrict__ ksum,
    const float* __restrict__ x0, float* __restrict__ att) {
  int b = blockIdx.x, h = blockIdx.y;
  int t = threadIdx.x;
  int lane = t & 63, wg = t >> 6;
  __shared__ float hn1[64], qh[64], qpart[4][64], red[4], pol[4][64];
  __shared__ float buf[272];
  __shared__ float dots[2048];
  __shared__ u16 vst[512 * 64];
  const float dn = 0.35355339059327373f;
  const float ratio = 1.0f / sqrtf(266.0f);

  if (t < 64) {  // LN1 at position 0 (one wave)
    float xv = x0[b * 64 + t];
    float mu = wredsum64(xv) * 0.015625f;
    float dv = xv - mu;
    float var = wredsum64(dv * dv) * 0.015625f;
    hn1[t] = dv * rsqrtf(var + 1e-5f) * ln1g[t] + ln1b[t];
  }
  __syncthreads();
  {
    float p = 0;
#pragma unroll
    for (int dd = 0; dd < 16; ++dd)
      p += hn1[wg * 16 + dd] * Wq[(wg * 16 + dd) * 512 + h * 64 + lane];
    qpart[wg][lane] = p;
  }
  __syncthreads();
  if (t < 64) qh[t] = qpart[0][t] + qpart[1][t] + qpart[2][t] + qpart[3][t];
  __syncthreads();

  if (h < 4) {
    int bh = b * 4 + h;
    float dq = 0;
#pragma unroll
    for (int d = 0; d < 64; ++d) dq += qh[d] * qh[d];
    dq *= 0.0625f;
    float lmax = -3e38f;
#pragma unroll
    for (int pass = 0; pass < 2; ++pass) {
      int m = t + pass * 256;
      if (m < NBF) {
        const float4* pp = reinterpret_cast<const float4*>(proj + m * 64);
        float s = 0;
#pragma unroll
        for (int q4 = 0; q4 < 16; ++q4) {
          float4 uu = pp[q4];
          s += qh[q4 * 4] * uu.x + qh[q4 * 4 + 1] * uu.y +
               qh[q4 * 4 + 2] * uu.z + qh[q4 * 4 + 3] * uu.w;
        }
        float dash = dn * s;
        buf[m] = dash;
        lmax = fmaxf(lmax, dash);
      }
    }
    float mxq = bmax256(lmax, red);
    float part = 0;
#pragma unroll
    for (int pass = 0; pass < 2; ++pass) {
      int m = t + pass * 256;
      if (m < NBF) {
        float qp = ratio * (expf(buf[m] - dq - mxq) + 1e-4f);
        buf[m] = qp;
        part += qp * ksum[(size_t)bh * NBF + m];
      }
    }
    float den = bsum256(part, red);
    __syncthreads();
    {
      float s = 0;
      for (int m = wg; m < NBF; m += 4)
        s += buf[m] * ctx[((size_t)bh * NBF + m) * 64 + lane];
      pol[wg][lane] = s;
    }
    __syncthreads();
    if (t < 64)
      att[b * 512 + h * 64 + t] =
          (pol[0][t] + pol[1][t] + pol[2][t] + pol[3][t]) / den;
  } else {
    int hl = h - 4;
    size_t base = (size_t)(b * 4 + hl) * NTOK;
    float lmax = -3e38f;
#pragma unroll
    for (int i = 0; i < 8; ++i) {
      int n1 = t + i * 256;
      const ushort4* kr4 = reinterpret_cast<const ushort4*>(Kl + (base + n1) * 64);
      float s = 0;
#pragma unroll
      for (int d4 = 0; d4 < 16; ++d4) {
        ushort4 uu = kr4[d4];
        s += qh[d4 * 4] * bf2f(uu.x) + qh[d4 * 4 + 1] * bf2f(uu.y) +
             qh[d4 * 4 + 2] * bf2f(uu.z) + qh[d4 * 4 + 3] * bf2f(uu.w);
      }
      float dv = s * 0.125f;
      if (ids[b * NTOK + n1] == 0) dv = -1e9f;
      dots[n1] = dv;
      lmax = fmaxf(lmax, dv);
    }
    float mxl = bmax256(lmax, red);
    float ps = 0;
#pragma unroll
    for (int i = 0; i < 8; ++i) {
      int n1 = t + i * 256;
      float p = expf(dots[n1] - mxl);
      dots[n1] = p;
      ps += p;
    }
    float sden = bsum256(ps, red);
    float acc = 0;
    for (int c = 0; c < 4; ++c) {
      __syncthreads();
      const ushort4* src = reinterpret_cast<const ushort4*>(Vl + (base + c * 512) * 64);
      ushort4* dst = reinterpret_cast<ushort4*>(vst);
#pragma unroll
      for (int i = 0; i < 32; ++i) dst[t + i * 256] = src[t + i * 256];
      __syncthreads();
      int r0 = wg * 128;
#pragma unroll 8
      for (int r = 0; r < 128; ++r)
        acc += dots[c * 512 + r0 + r] * bf2f(vst[(r0 + r) * 64 + lane]);
    }
    __syncthreads();
    pol[wg][lane] = acc;
    __syncthreads();
    if (t < 64)
      att[b * 512 + h * 64 + t] =
          (pol[0][t] + pol[1][t] + pol[2][t] + pol[3][t]) / sden;
  }
}

// ---------------- tail at position 0: Wo, FF, final LN, heads ----------------
__global__ __launch_bounds__(256) void k_fin2(
    const float* __restrict__ ln2g, const float* __restrict__ ln2b,
    const float* __restrict__ Wo,
    const float* __restrict__ W1, const float* __restrict__ b1,
    const float* __restrict__ W2, const float* __restrict__ b2,
    const float* __restrict__ lnfg, const float* __restrict__ lnfb,
    const float* __restrict__ Wout, const float* __restrict__ bout,
    const float* __restrict__ Wc1, const float* __restrict__ bc1,
    const float* __restrict__ Wc2, const float* __restrict__ bc2,
    const float* __restrict__ x0, const float* __restrict__ att,
    float* __restrict__ out) {
  int b = blockIdx.x;
  int t = threadIdx.x;
  int lane = t & 63, wg = t >> 6;
  __shared__ float o512s[512], x0s[64], part[4][64];
  __shared__ float y1[64], hn2[64], gact[256], hfin[64], repS[64], c1s[32];
  o512s[t] = att[b * 512 + t];
  o512s[t + 256] = att[b * 512 + t + 256];
  if (t < 64) x0s[t] = x0[b * 64 + t];
  __syncthreads();
  {
    float s = 0;
#pragma unroll 4
    for (int c = wg * 128; c < wg * 128 + 128; ++c) s += o512s[c] * Wo[c * 64 + lane];
    part[wg][lane] = s;
  }
  __syncthreads();
  if (t < 64) {
    float yv = x0s[t] + part[0][t] + part[1][t] + part[2][t] + part[3][t];
    y1[t] = yv;
    float mu = wredsum64(yv) * 0.015625f;
    float dv = yv - mu;
    float var = wredsum64(dv * dv) * 0.015625f;
    hn2[t] = dv * rsqrtf(var + 1e-5f) * ln2g[t] + ln2b[t];
  }
  __syncthreads();
  {
    float s = b1[t];
#pragma unroll 4
    for (int d = 0; d < 64; ++d) s += hn2[d] * W1[d * 256 + t];
    gact[t] = 0.5f * s * (1.f + erff(s * 0.7071067811865475f));
  }
  __syncthreads();
  {
    float s = 0;
#pragma unroll 4
    for (int j = wg * 64; j < wg * 64 + 64; ++j) s += gact[j] * W2[j * 64 + lane];
    part[wg][lane] = s;
  }
  __syncthreads();
  if (t < 64) {
    float y2 = x0s[t] + b2[t] + part[0][t] + part[1][t] + part[2][t] + part[3][t];
    float hm = 0.5f * (y1[t] + y2);
    float mu = wredsum64(hm) * 0.015625f;
    float dv = hm - mu;
    float var = wredsum64(dv * dv) * 0.015625f;
    hfin[t] = dv * rsqrtf(var + 1e-5f) * lnfg[t] + lnfb[t];
  }
  __syncthreads();
  {
    float s = 0;
#pragma unroll
    for (int dd = 0; dd < 16; ++dd)
      s += hfin[wg * 16 + dd] * Wout[(wg * 16 + dd) * 64 + lane];
    part[wg][lane] = s;
  }
  __syncthreads();
  if (t < 64) {
    float s = bout[t] + part[0][t] + part[1][t] + part[2][t] + part[3][t];
    repS[t] = s;
    out[16 + b * 64 + t] = s;
  }
  __syncthreads();
  if (t < 32) {
    float s = bc1[t];
#pragma unroll 4
    for (int d = 0; d < 64; ++d) s += repS[d] * Wc1[d * 32 + t];
    c1s[t] = fmaxf(s, 0.f);
  }
  __syncthreads();
  if (t < 2) {
    float s = bc2[t];
#pragma unroll
    for (int jj = 0; jj < 32; ++jj) s += c1s[jj] * Wc2[jj * 2 + t];
    out[b * 2 + t] = s;
  }
}

extern "C" void kernel_launch(void* const* d_in, const int* in_sizes, int n_in,
                              void* d_out, int out_size, void* d_ws, size_t ws_size,
                              hipStream_t stream) {
  (void)in_sizes; (void)n_in; (void)out_size; (void)ws_size;
  const int* ids = (const int*)d_in[0];
  const float* tok = (const float*)d_in[1];
  const float* ln1g = (const float*)d_in[2];
  const float* ln1b = (const float*)d_in[3];
  const float* Wq = (const float*)d_in[4];
  const float* Wk = (const float*)d_in[5];
  const float* Wv = (const float*)d_in[6];
  const float* Wo = (const float*)d_in[7];
  const float* ln2g = (const float*)d_in[8];
  const float* ln2b = (const float*)d_in[9];
  const float* W1 = (const float*)d_in[10];
  const float* b1 = (const float*)d_in[11];
  const float* W2 = (const float*)d_in[12];
  const float* b2 = (const float*)d_in[13];
  const float* lnfg = (const float*)d_in[14];
  const float* lnfb = (const float*)d_in[15];
  const float* Wout = (const float*)d_in[16];
  const float* bout = (const float*)d_in[17];
  const float* Wc1 = (const float*)d_in[18];
  const float* bc1 = (const float*)d_in[19];
  const float* Wc2 = (const float*)d_in[20];
  const float* bc2 = (const float*)d_in[21];
  const float* proj = (const float*)d_in[22];

  uint8_t* w = (uint8_t*)d_ws;
  size_t off = 0;
  const size_t big = (size_t)8 * 4 * NTOK * 64 * 2;  // 8.39 MB each
  u16* Kg = (u16*)(w + off); off += big;
  u16* Vg = (u16*)(w + off); off += big;
  u16* Kl = (u16*)(w + off); off += big;
  u16* Vl = (u16*)(w + off); off += big;
  float* diagK = (float*)(w + off); off += (size_t)8 * 4 * NTOK * 4;
  float* ctx = (float*)(w + off); off += (size_t)8 * 4 * NBF * 64 * 4;
  float* ksum = (float*)(w + off); off += (size_t)8 * 4 * NBF * 4;
  unsigned int* gmax = (unsigned int*)(w + off); off += 4;
  float* x0 = (float*)(w + off); off += 64 * 8 * 4;
  float* att = (float*)(w + off); off += (size_t)8 * 512 * 4;

  // zero accumulators + gmax (contiguous: ctx, ksum, gmax)
  hipMemsetAsync(ctx, 0,
                 (size_t)8 * 4 * NBF * 64 * 4 + (size_t)8 * 4 * NBF * 4 + 4, stream);
  k_prep<<<8 * 512, 64, 0, stream>>>(ids, tok, ln1g, ln1b, Wk, Wv, Kg, Vg, Kl, Vl,
                                     diagK, x0);
  k_max<<<dim3(32, 8), 256, 0, stream>>>(Kg, proj, gmax);
  k_ctx<<<dim3(32, 8), 256, 0, stream>>>(Kg, Vg, diagK, proj, gmax, ctx, ksum);
  k_att<<<dim3(8, 8), 256, 0, stream>>>(ids, ln1g, ln1b, Wq, proj, Kl, Vl, ctx,
                                        ksum, x0, att);
  k_fin2<<<8, 256, 0, stream>>>(ln2g, ln2b, Wo, W1, b1, W2, b2, lnfg, lnfb, Wout,
                                bout, Wc1, bc1, Wc2, bc2, x0, att, (float*)d_out);
}

// Round 7
// 170.656 us; speedup vs baseline: 10.0982x; 1.0048x over previous
//
#include <hip/hip_runtime.h>
#include <math.h>

#define NTOK 2048
#define NBF 266
#define MPAD 272

typedef unsigned short u16;
typedef __attribute__((ext_vector_type(8))) short short8;
typedef __attribute__((ext_vector_type(4))) float f32x4;

__device__ __forceinline__ float bf2f(u16 u) {
  unsigned int x = ((unsigned int)u) << 16;
  return __uint_as_float(x);
}
__device__ __forceinline__ u16 f2bf(float f) {
  unsigned int x = __float_as_uint(f);
  unsigned int r = x + 0x7FFFu + ((x >> 16) & 1u);
  return (u16)(r >> 16);
}
__device__ __forceinline__ float wredsum64(float v) {
  for (int o = 32; o > 0; o >>= 1) v += __shfl_xor(v, o);
  return v;
}
__device__ __forceinline__ float bsum256(float v, float* red) {
  for (int o = 32; o > 0; o >>= 1) v += __shfl_xor(v, o);
  __syncthreads();
  if ((threadIdx.x & 63) == 0) red[threadIdx.x >> 6] = v;
  __syncthreads();
  return red[0] + red[1] + red[2] + red[3];
}
__device__ __forceinline__ float bmax256(float v, float* red) {
  for (int o = 32; o > 0; o >>= 1) v = fmaxf(v, __shfl_xor(v, o));
  __syncthreads();
  if ((threadIdx.x & 63) == 0) red[threadIdx.x >> 6] = v;
  __syncthreads();
  return fmaxf(fmaxf(red[0], red[1]), fmaxf(red[2], red[3]));
}
#define INVF_C 0.4152410118609190f

// ---- prep: x, LN1 -> hn (bf16 out), GLOBAL-head K (rotary)+diag, Vg mask ---
// Local heads need no K/V materialization (folded into k_att via reordering).
__global__ __launch_bounds__(64) void k_prep(
    const int* __restrict__ ids, const float* __restrict__ tok_emb,
    const float* __restrict__ ln1g, const float* __restrict__ ln1b,
    const float* __restrict__ Wk, const float* __restrict__ Wv,
    u16* __restrict__ Kg, u16* __restrict__ Vg, u16* __restrict__ hng,
    float* __restrict__ diagK, float* __restrict__ x0) {
  int blk = blockIdx.x;            // 8 * 256 blocks
  int b = blk >> 8, nt = blk & 255;
  int n0 = nt * 8;
  int t = threadIdx.x;
  __shared__ float hn[8][64];
  int idv[8];
  float g = ln1g[t], bb = ln1b[t];
  float invp = exp2f(-INVF_C * (float)(t & 31));
#pragma unroll
  for (int j = 0; j < 8; ++j) {
    int n = n0 + j;
    int id = ids[b * NTOK + n];
    idv[j] = id;
    float ang = (float)n * invp;
    float pv = (t < 32) ? sinf(ang) : cosf(ang);
    float xv = tok_emb[id * 64 + t] + pv;
    float mu = wredsum64(xv) * 0.015625f;
    float dv = xv - mu;
    float var = wredsum64(dv * dv) * 0.015625f;
    float hv = dv * rsqrtf(var + 1e-5f) * g + bb;
    hn[j][t] = hv;
    hng[((size_t)b * NTOK + n) * 64 + t] = f2bf(hv);
    if (n == 0) x0[b * 64 + t] = xv;
  }
  __syncthreads();

  // only global-head columns: Wk[:,0:256] (t<32) or Wv[:,0:256] (t>=32)
  float acc[8][8];
#pragma unroll
  for (int j = 0; j < 8; ++j)
#pragma unroll
    for (int i = 0; i < 8; ++i) acc[j][i] = 0.f;
  const float* wsrc = (t < 32) ? (Wk + t * 8) : (Wv + (t - 32) * 8);
  for (int d2 = 0; d2 < 64; ++d2) {
    float4 w0 = *reinterpret_cast<const float4*>(wsrc + d2 * 512);
    float4 w1 = *reinterpret_cast<const float4*>(wsrc + d2 * 512 + 4);
#pragma unroll
    for (int j = 0; j < 8; ++j) {
      float hv = hn[j][d2];
      acc[j][0] += hv * w0.x; acc[j][1] += hv * w0.y;
      acc[j][2] += hv * w0.z; acc[j][3] += hv * w0.w;
      acc[j][4] += hv * w1.x; acc[j][5] += hv * w1.y;
      acc[j][6] += hv * w1.z; acc[j][7] += hv * w1.w;
    }
  }

  if (t < 32) {                   // K-global: rotary, diag, write Kg
    int hh = t >> 3, db = (t & 7) * 8;
    float invf[4];
#pragma unroll
    for (int p = 0; p < 4; ++p)
      invf[p] = exp2f(-INVF_C * (float)((db >> 1) + p));
#pragma unroll
    for (int j = 0; j < 8; ++j) {
      int n = n0 + j;
      float kr[8];
#pragma unroll
      for (int p = 0; p < 4; ++p) {
        float ang = (float)n * invf[p];
        float sv = sinf(ang), cv = cosf(ang);
        float e0 = acc[j][2 * p], e1 = acc[j][2 * p + 1];
        kr[2 * p] = e0 * cv - e1 * sv;
        kr[2 * p + 1] = e1 * cv + e0 * sv;
      }
      float dq = 0;
#pragma unroll
      for (int i = 0; i < 8; ++i) dq += kr[i] * kr[i];
      dq += __shfl_xor(dq, 1);
      dq += __shfl_xor(dq, 2);
      dq += __shfl_xor(dq, 4);
      size_t hb = (size_t)(b * 4 + hh) * NTOK + n;
      if ((t & 7) == 0) diagK[hb] = dq * 0.0625f;  // 0.5*dn*dn
      size_t base = hb * 64 + db;
      ushort4 s0, s1;
      s0.x = f2bf(kr[0]); s0.y = f2bf(kr[1]); s0.z = f2bf(kr[2]); s0.w = f2bf(kr[3]);
      s1.x = f2bf(kr[4]); s1.y = f2bf(kr[5]); s1.z = f2bf(kr[6]); s1.w = f2bf(kr[7]);
      *reinterpret_cast<ushort4*>(Kg + base) = s0;
      *reinterpret_cast<ushort4*>(Kg + base + 4) = s1;
    }
  } else {                        // V-global: mask, write Vg
    int tv = t - 32;
    int hh = tv >> 3, db = (tv & 7) * 8;
#pragma unroll
    for (int j = 0; j < 8; ++j) {
      int n = n0 + j;
      float maskf = (idv[j] != 0) ? 1.f : 0.f;
      size_t base = ((size_t)(b * 4 + hh) * NTOK + n) * 64 + db;
      ushort4 m0, m1;
      m0.x = f2bf(acc[j][0] * maskf); m0.y = f2bf(acc[j][1] * maskf);
      m0.z = f2bf(acc[j][2] * maskf); m0.w = f2bf(acc[j][3] * maskf);
      m1.x = f2bf(acc[j][4] * maskf); m1.y = f2bf(acc[j][5] * maskf);
      m1.z = f2bf(acc[j][6] * maskf); m1.w = f2bf(acc[j][7] * maskf);
      *reinterpret_cast<ushort4*>(Vg + base) = m0;
      *reinterpret_cast<ushort4*>(Vg + base + 4) = m1;
    }
  }
}

// ---- helper: stage proj (f32) into swizzled bf16 LDS [MPAD][64] ------------
__device__ __forceinline__ void stage_prj(const float* __restrict__ proj,
                                          u16* prjbf, int t) {
  for (int c = t; c < MPAD * 8; c += 256) {   // 16B chunks
    int m = c >> 3, k0 = (c & 7) * 8;
    int e = (m * 64 + k0) ^ ((m & 7) << 3);
    uint4 pk;
    if (m < NBF) {
      const float4* ps = reinterpret_cast<const float4*>(proj + m * 64 + k0);
      float4 p0 = ps[0], p1 = ps[1];
      pk.x = (unsigned)f2bf(p0.x) | ((unsigned)f2bf(p0.y) << 16);
      pk.y = (unsigned)f2bf(p0.z) | ((unsigned)f2bf(p0.w) << 16);
      pk.z = (unsigned)f2bf(p1.x) | ((unsigned)f2bf(p1.y) << 16);
      pk.w = (unsigned)f2bf(p1.z) | ((unsigned)f2bf(p1.w) << 16);
    } else {
      pk.x = pk.y = pk.z = pk.w = 0u;
    }
    *reinterpret_cast<uint4*>(&prjbf[e]) = pk;
  }
}

// ---------------- global max over dash = dn * Kg @ proj^T (MFMA) ------------
__global__ __launch_bounds__(256) void k_max(
    const u16* __restrict__ Kg, const float* __restrict__ proj,
    unsigned int* __restrict__ gmax) {
  int bh = blockIdx.x, ns = blockIdx.y;
  int t = threadIdx.x, lane = t & 63, w = t >> 6;
  __shared__ __align__(16) u16 prjbf[MPAD * 64];
  __shared__ __align__(16) u16 kbf[64 * 64];
  __shared__ float red[4];
  stage_prj(proj, prjbf, t);
  float mv = -3e38f;
  int ko = (lane >> 4) * 8;
  for (int c4 = 0; c4 < 4; ++c4) {
    int nb = ns * 256 + c4 * 64;
    __syncthreads();
    for (int p = 0; p < 2; ++p) {
      int idx = t + p * 256;
      int n = idx >> 3, k0 = (idx & 7) * 8;
      uint4 src = *reinterpret_cast<const uint4*>(
          Kg + ((size_t)bh * NTOK + nb + n) * 64 + k0);
      *reinterpret_cast<uint4*>(&kbf[(n * 64 + k0) ^ ((n & 7) << 3)]) = src;
    }
    __syncthreads();
    int nl = w * 16 + (lane & 15);
    short8 a0 = *reinterpret_cast<const short8*>(&kbf[(nl * 64 + ko) ^ ((nl & 7) << 3)]);
    short8 a1 = *reinterpret_cast<const short8*>(&kbf[(nl * 64 + ko + 32) ^ ((nl & 7) << 3)]);
#pragma unroll
    for (int mt = 0; mt < 17; ++mt) {
      int m = mt * 16 + (lane & 15);
      short8 b0 = *reinterpret_cast<const short8*>(&prjbf[(m * 64 + ko) ^ ((m & 7) << 3)]);
      short8 b1 = *reinterpret_cast<const short8*>(&prjbf[(m * 64 + ko + 32) ^ ((m & 7) << 3)]);
      f32x4 d = {0.f, 0.f, 0.f, 0.f};
      d = __builtin_amdgcn_mfma_f32_16x16x32_bf16(a0, b0, d, 0, 0, 0);
      d = __builtin_amdgcn_mfma_f32_16x16x32_bf16(a1, b1, d, 0, 0, 0);
      if (m < NBF) {
        mv = fmaxf(mv, fmaxf(fmaxf(d[0], d[1]), fmaxf(d[2], d[3])));
      }
    }
  }
  mv *= 0.35355339059327373f;
  for (int o = 32; o > 0; o >>= 1) mv = fmaxf(mv, __shfl_xor(mv, o));
  __syncthreads();
  if (lane == 0) red[w] = mv;
  __syncthreads();
  if (t == 0) {
    float m2 = fmaxf(fmaxf(red[0], red[1]), fmaxf(red[2], red[3]));
    unsigned int b = __float_as_uint(m2);
    unsigned int u = (b & 0x80000000u) ? ~b : (b | 0x80000000u);
    atomicMax(gmax, u);
  }
}

// ---------------- ctx = kp^T @ Vg, ksum = sum_n kp (MFMA) -------------------
__global__ __launch_bounds__(256) void k_ctx(
    const u16* __restrict__ Kg, const u16* __restrict__ Vg,
    const float* __restrict__ diagK, const float* __restrict__ proj,
    const unsigned int* __restrict__ gmax,
    float* __restrict__ ctx, float* __restrict__ ksum) {
  int bh = blockIdx.x, ns = blockIdx.y;
  int t = threadIdx.x, lane = t & 63, w = t >> 6;
  __shared__ __align__(16) u16 prjbf[MPAD * 64];
  __shared__ __align__(16) u16 kpT[MPAD * 64];
  __shared__ __align__(16) u16 kbf[64 * 64];
  __shared__ __align__(16) u16 vbT[64 * 64];
  __shared__ float dg[64];
  __shared__ float ksl[MPAD];
  stage_prj(proj, prjbf, t);
  if (t < MPAD - 256) ksl[256 + t] = 0.f;
  ksl[t] = 0.f;
  unsigned int u = *gmax;
  unsigned int bb = (u & 0x80000000u) ? (u & 0x7FFFFFFFu) : ~u;
  float mx = __uint_as_float(bb);
  const float dn = 0.35355339059327373f;
  const float ratio = 1.0f / sqrtf(266.0f);
  int ko = (lane >> 4) * 8;
  f32x4 acc[17];
#pragma unroll
  for (int i = 0; i < 17; ++i) acc[i] = (f32x4){0.f, 0.f, 0.f, 0.f};

  for (int c4 = 0; c4 < 4; ++c4) {
    int nb = ns * 256 + c4 * 64;
    for (int p = 0; p < 2; ++p) {
      int idx = t + p * 256;
      int n = idx >> 3, k0 = (idx & 7) * 8;
      uint4 src = *reinterpret_cast<const uint4*>(
          Kg + ((size_t)bh * NTOK + nb + n) * 64 + k0);
      *reinterpret_cast<uint4*>(&kbf[(n * 64 + k0) ^ ((n & 7) << 3)]) = src;
      uint4 vv = *reinterpret_cast<const uint4*>(
          Vg + ((size_t)bh * NTOK + nb + n) * 64 + k0);
      u16 pv[8];
      *reinterpret_cast<uint4*>(pv) = vv;
#pragma unroll
      for (int i = 0; i < 8; ++i) {
        int d = k0 + i;
        vbT[(d * 64 + n) ^ ((d & 7) << 3)] = pv[i];
      }
    }
    if (t < 64) dg[t] = diagK[(size_t)bh * NTOK + nb + t];
    __syncthreads();
    {
      int nl = w * 16 + (lane & 15);
      short8 a0 = *reinterpret_cast<const short8*>(&kbf[(nl * 64 + ko) ^ ((nl & 7) << 3)]);
      short8 a1 = *reinterpret_cast<const short8*>(&kbf[(nl * 64 + ko + 32) ^ ((nl & 7) << 3)]);
      float dgv[4];
#pragma unroll
      for (int r = 0; r < 4; ++r) dgv[r] = dg[w * 16 + (lane >> 4) * 4 + r];
      int n0 = w * 16 + (lane >> 4) * 4;
#pragma unroll
      for (int mt = 0; mt < 17; ++mt) {
        int m = mt * 16 + (lane & 15);
        short8 b0 = *reinterpret_cast<const short8*>(&prjbf[(m * 64 + ko) ^ ((m & 7) << 3)]);
        short8 b1 = *reinterpret_cast<const short8*>(&prjbf[(m * 64 + ko + 32) ^ ((m & 7) << 3)]);
        f32x4 d = {0.f, 0.f, 0.f, 0.f};
        d = __builtin_amdgcn_mfma_f32_16x16x32_bf16(a0, b0, d, 0, 0, 0);
        d = __builtin_amdgcn_mfma_f32_16x16x32_bf16(a1, b1, d, 0, 0, 0);
        float kp0 = ratio * (expf(dn * d[0] - dgv[0] - mx) + 1e-4f);
        float kp1 = ratio * (expf(dn * d[1] - dgv[1] - mx) + 1e-4f);
        float kp2 = ratio * (expf(dn * d[2] - dgv[2] - mx) + 1e-4f);
        float kp3 = ratio * (expf(dn * d[3] - dgv[3] - mx) + 1e-4f);
        ushort4 pkk;
        pkk.x = f2bf(kp0); pkk.y = f2bf(kp1); pkk.z = f2bf(kp2); pkk.w = f2bf(kp3);
        *reinterpret_cast<ushort4*>(&kpT[(m * 64 + n0) ^ ((m & 7) << 3)]) = pkk;
        float ksp = kp0 + kp1 + kp2 + kp3;
        ksp += __shfl_xor(ksp, 16);
        ksp += __shfl_xor(ksp, 32);
        if (lane < 16) atomicAdd(&ksl[mt * 16 + lane], ksp);
      }
    }
    __syncthreads();
    {
      int dcol = w * 16 + (lane & 15);
      short8 vb0 = *reinterpret_cast<const short8*>(&vbT[(dcol * 64 + ko) ^ ((dcol & 7) << 3)]);
      short8 vb1 = *reinterpret_cast<const short8*>(&vbT[(dcol * 64 + ko + 32) ^ ((dcol & 7) << 3)]);
#pragma unroll
      for (int mt = 0; mt < 17; ++mt) {
        int m = mt * 16 + (lane & 15);
        short8 a0 = *reinterpret_cast<const short8*>(&kpT[(m * 64 + ko) ^ ((m & 7) << 3)]);
        short8 a1 = *reinterpret_cast<const short8*>(&kpT[(m * 64 + ko + 32) ^ ((m & 7) << 3)]);
        acc[mt] = __builtin_amdgcn_mfma_f32_16x16x32_bf16(a0, vb0, acc[mt], 0, 0, 0);
        acc[mt] = __builtin_amdgcn_mfma_f32_16x16x32_bf16(a1, vb1, acc[mt], 0, 0, 0);
      }
    }
    __syncthreads();
  }
  int dcol = w * 16 + (lane & 15);
#pragma unroll
  for (int mt = 0; mt < 17; ++mt) {
#pragma unroll
    for (int r = 0; r < 4; ++r) {
      int m = mt * 16 + (lane >> 4) * 4 + r;
      if (m < NBF)
        atomicAdd(&ctx[((size_t)bh * NBF + m) * 64 + dcol], acc[mt][r]);
    }
  }
  __syncthreads();
  for (int c = t; c < NBF; c += 256)
    atomicAdd(&ksum[(size_t)bh * NBF + c], ksl[c]);
}

// ---------------- attention row 0, one block per (b, head) ------------------
__global__ __launch_bounds__(256) void k_att(
    const int* __restrict__ ids,
    const float* __restrict__ ln1g, const float* __restrict__ ln1b,
    const float* __restrict__ Wq, const float* __restrict__ Wk,
    const float* __restrict__ Wv, const float* __restrict__ proj,
    const u16* __restrict__ hng,
    const float* __restrict__ ctx, const float* __restrict__ ksum,
    const float* __restrict__ x0, float* __restrict__ att) {
  int b = blockIdx.x, h = blockIdx.y;
  int t = threadIdx.x;
  int lane = t & 63, wg = t >> 6;
  __shared__ float hn1[64], qh[64], qpart[4][64], red[4], pol[4][64];
  __shared__ float buf[272];
  __shared__ float dots[2048];
  __shared__ float wkq[64], svec[64];
  const float dn = 0.35355339059327373f;
  const float ratio = 1.0f / sqrtf(266.0f);

  if (t < 64) {  // LN1 at position 0 (one wave, f32 x0)
    float xv = x0[b * 64 + t];
    float mu = wredsum64(xv) * 0.015625f;
    float dv = xv - mu;
    float var = wredsum64(dv * dv) * 0.015625f;
    hn1[t] = dv * rsqrtf(var + 1e-5f) * ln1g[t] + ln1b[t];
  }
  __syncthreads();
  {
    float p = 0;
#pragma unroll
    for (int dd = 0; dd < 16; ++dd)
      p += hn1[wg * 16 + dd] * Wq[(wg * 16 + dd) * 512 + h * 64 + lane];
    qpart[wg][lane] = p;
  }
  __syncthreads();
  if (t < 64) qh[t] = qpart[0][t] + qpart[1][t] + qpart[2][t] + qpart[3][t];
  __syncthreads();

  if (h < 4) {
    // ---- global (Performer) head ----
    int bh = b * 4 + h;
    float dq = 0;
#pragma unroll
    for (int d = 0; d < 64; ++d) dq += qh[d] * qh[d];
    dq *= 0.0625f;
    float lmax = -3e38f;
#pragma unroll
    for (int pass = 0; pass < 2; ++pass) {
      int m = t + pass * 256;
      if (m < NBF) {
        const float4* pp = reinterpret_cast<const float4*>(proj + m * 64);
        float s = 0;
#pragma unroll
        for (int q4 = 0; q4 < 16; ++q4) {
          float4 uu = pp[q4];
          s += qh[q4 * 4] * uu.x + qh[q4 * 4 + 1] * uu.y +
               qh[q4 * 4 + 2] * uu.z + qh[q4 * 4 + 3] * uu.w;
        }
        float dash = dn * s;
        buf[m] = dash;
        lmax = fmaxf(lmax, dash);
      }
    }
    float mxq = bmax256(lmax, red);
    float part = 0;
#pragma unroll
    for (int pass = 0; pass < 2; ++pass) {
      int m = t + pass * 256;
      if (m < NBF) {
        float qp = ratio * (expf(buf[m] - dq - mxq) + 1e-4f);
        buf[m] = qp;
        part += qp * ksum[(size_t)bh * NBF + m];
      }
    }
    float den = bsum256(part, red);
    __syncthreads();
    {
      float s = 0;
      for (int m = wg; m < NBF; m += 4)
        s += buf[m] * ctx[((size_t)bh * NBF + m) * 64 + lane];
      pol[wg][lane] = s;
    }
    __syncthreads();
    if (t < 64)
      att[b * 512 + h * 64 + t] =
          (pol[0][t] + pol[1][t] + pol[2][t] + pol[3][t]) / den;
  } else {
    // ---- local (softmax) head, K/V folded: dots = hn·(Wk_h q), ol=(Σp·hn)Wv_h
    int ch = h * 64;  // column offset of this head in Wk/Wv
    if (t < 64) {
      float s = 0;
#pragma unroll 8
      for (int j = 0; j < 64; ++j) s += Wk[t * 512 + ch + j] * qh[j];
      wkq[t] = s;
    }
    __syncthreads();
    const u16* hnb = hng + (size_t)b * NTOK * 64;
    float lmax = -3e38f;
#pragma unroll
    for (int i = 0; i < 8; ++i) {
      int n1 = t + i * 256;
      const ushort4* hr = reinterpret_cast<const ushort4*>(hnb + (size_t)n1 * 64);
      float s = 0;
#pragma unroll
      for (int d4 = 0; d4 < 16; ++d4) {
        ushort4 uu = hr[d4];
        s += wkq[d4 * 4] * bf2f(uu.x) + wkq[d4 * 4 + 1] * bf2f(uu.y) +
             wkq[d4 * 4 + 2] * bf2f(uu.z) + wkq[d4 * 4 + 3] * bf2f(uu.w);
      }
      float dv = s * 0.125f;
      if (ids[b * NTOK + n1] == 0) dv = -1e9f;
      dots[n1] = dv;
      lmax = fmaxf(lmax, dv);
    }
    float mxl = bmax256(lmax, red);
    float ps = 0;
#pragma unroll
    for (int i = 0; i < 8; ++i) {
      int n1 = t + i * 256;
      float p = expf(dots[n1] - mxl);
      dots[n1] = p;
      ps += p;
    }
    float sden = bsum256(ps, red);
    // s[d] = sum_n p_n hn[n][d]; wave wg covers rows wg*512..+511
    float acc = 0;
#pragma unroll 4
    for (int r = 0; r < 512; ++r) {
      int n1 = wg * 512 + r;
      acc += dots[n1] * bf2f(hnb[(size_t)n1 * 64 + lane]);
    }
    __syncthreads();
    pol[wg][lane] = acc;
    __syncthreads();
    if (t < 64) svec[t] = pol[0][t] + pol[1][t] + pol[2][t] + pol[3][t];
    __syncthreads();
    {  // ol[j] = (svec @ Wv_h)[j] / sden ; j = lane, partial over d-range
      float p2 = 0;
#pragma unroll
      for (int dd = 0; dd < 16; ++dd)
        p2 += svec[wg * 16 + dd] * Wv[(wg * 16 + dd) * 512 + ch + lane];
      pol[wg][lane] = p2;
    }
    __syncthreads();
    if (t < 64)
      att[b * 512 + h * 64 + t] =
          (pol[0][t] + pol[1][t] + pol[2][t] + pol[3][t]) / sden;
  }
}

// ---------------- tail at position 0: Wo, FF, final LN, heads ----------------
__global__ __launch_bounds__(256) void k_fin2(
    const float* __restrict__ ln2g, const float* __restrict__ ln2b,
    const float* __restrict__ Wo,
    const float* __restrict__ W1, const float* __restrict__ b1,
    const float* __restrict__ W2, const float* __restrict__ b2,
    const float* __restrict__ lnfg, const float* __restrict__ lnfb,
    const float* __restrict__ Wout, const float* __restrict__ bout,
    const float* __restrict__ Wc1, const float* __restrict__ bc1,
    const float* __restrict__ Wc2, const float* __restrict__ bc2,
    const float* __restrict__ x0, const float* __restrict__ att,
    float* __restrict__ out) {
  int b = blockIdx.x;
  int t = threadIdx.x;
  int lane = t & 63, wg = t >> 6;
  __shared__ float o512s[512], x0s[64], part[4][64];
  __shared__ float y1[64], hn2[64], gact[256], hfin[64], repS[64], c1s[32];
  o512s[t] = att[b * 512 + t];
  o512s[t + 256] = att[b * 512 + t + 256];
  if (t < 64) x0s[t] = x0[b * 64 + t];
  __syncthreads();
  {
    float s = 0;
#pragma unroll 4
    for (int c = wg * 128; c < wg * 128 + 128; ++c) s += o512s[c] * Wo[c * 64 + lane];
    part[wg][lane] = s;
  }
  __syncthreads();
  if (t < 64) {
    float yv = x0s[t] + part[0][t] + part[1][t] + part[2][t] + part[3][t];
    y1[t] = yv;
    float mu = wredsum64(yv) * 0.015625f;
    float dv = yv - mu;
    float var = wredsum64(dv * dv) * 0.015625f;
    hn2[t] = dv * rsqrtf(var + 1e-5f) * ln2g[t] + ln2b[t];
  }
  __syncthreads();
  {
    float s = b1[t];
#pragma unroll 4
    for (int d = 0; d < 64; ++d) s += hn2[d] * W1[d * 256 + t];
    gact[t] = 0.5f * s * (1.f + erff(s * 0.7071067811865475f));
  }
  __syncthreads();
  {
    float s = 0;
#pragma unroll 4
    for (int j = wg * 64; j < wg * 64 + 64; ++j) s += gact[j] * W2[j * 64 + lane];
    part[wg][lane] = s;
  }
  __syncthreads();
  if (t < 64) {
    float y2 = x0s[t] + b2[t] + part[0][t] + part[1][t] + part[2][t] + part[3][t];
    float hm = 0.5f * (y1[t] + y2);
    float mu = wredsum64(hm) * 0.015625f;
    float dv = hm - mu;
    float var = wredsum64(dv * dv) * 0.015625f;
    hfin[t] = dv * rsqrtf(var + 1e-5f) * lnfg[t] + lnfb[t];
  }
  __syncthreads();
  {
    float s = 0;
#pragma unroll
    for (int dd = 0; dd < 16; ++dd)
      s += hfin[wg * 16 + dd] * Wout[(wg * 16 + dd) * 64 + lane];
    part[wg][lane] = s;
  }
  __syncthreads();
  if (t < 64) {
    float s = bout[t] + part[0][t] + part[1][t] + part[2][t] + part[3][t];
    repS[t] = s;
    out[16 + b * 64 + t] = s;
  }
  __syncthreads();
  if (t < 32) {
    float s = bc1[t];
#pragma unroll 4
    for (int d = 0; d < 64; ++d) s += repS[d] * Wc1[d * 32 + t];
    c1s[t] = fmaxf(s, 0.f);
  }
  __syncthreads();
  if (t < 2) {
    float s = bc2[t];
#pragma unroll
    for (int jj = 0; jj < 32; ++jj) s += c1s[jj] * Wc2[jj * 2 + t];
    out[b * 2 + t] = s;
  }
}

extern "C" void kernel_launch(void* const* d_in, const int* in_sizes, int n_in,
                              void* d_out, int out_size, void* d_ws, size_t ws_size,
                              hipStream_t stream) {
  (void)in_sizes; (void)n_in; (void)out_size; (void)ws_size;
  const int* ids = (const int*)d_in[0];
  const float* tok = (const float*)d_in[1];
  const float* ln1g = (const float*)d_in[2];
  const float* ln1b = (const float*)d_in[3];
  const float* Wq = (const float*)d_in[4];
  const float* Wk = (const float*)d_in[5];
  const float* Wv = (const float*)d_in[6];
  const float* Wo = (const float*)d_in[7];
  const float* ln2g = (const float*)d_in[8];
  const float* ln2b = (const float*)d_in[9];
  const float* W1 = (const float*)d_in[10];
  const float* b1 = (const float*)d_in[11];
  const float* W2 = (const float*)d_in[12];
  const float* b2 = (const float*)d_in[13];
  const float* lnfg = (const float*)d_in[14];
  const float* lnfb = (const float*)d_in[15];
  const float* Wout = (const float*)d_in[16];
  const float* bout = (const float*)d_in[17];
  const float* Wc1 = (const float*)d_in[18];
  const float* bc1 = (const float*)d_in[19];
  const float* Wc2 = (const float*)d_in[20];
  const float* bc2 = (const float*)d_in[21];
  const float* proj = (const float*)d_in[22];

  uint8_t* w = (uint8_t*)d_ws;
  size_t off = 0;
  const size_t big = (size_t)8 * 4 * NTOK * 64 * 2;  // 8.39 MB each
  u16* Kg = (u16*)(w + off); off += big;
  u16* Vg = (u16*)(w + off); off += big;
  u16* hng = (u16*)(w + off); off += (size_t)8 * NTOK * 64 * 2;  // 2 MB
  float* diagK = (float*)(w + off); off += (size_t)8 * 4 * NTOK * 4;
  float* ctx = (float*)(w + off); off += (size_t)8 * 4 * NBF * 64 * 4;
  float* ksum = (float*)(w + off); off += (size_t)8 * 4 * NBF * 4;
  unsigned int* gmax = (unsigned int*)(w + off); off += 4;
  float* x0 = (float*)(w + off); off += 64 * 8 * 4;
  float* att = (float*)(w + off); off += (size_t)8 * 512 * 4;

  // zero accumulators + gmax (contiguous: ctx, ksum, gmax)
  hipMemsetAsync(ctx, 0,
                 (size_t)8 * 4 * NBF * 64 * 4 + (size_t)8 * 4 * NBF * 4 + 4, stream);
  k_prep<<<8 * 256, 64, 0, stream>>>(ids, tok, ln1g, ln1b, Wk, Wv, Kg, Vg, hng,
                                     diagK, x0);
  k_max<<<dim3(32, 8), 256, 0, stream>>>(Kg, proj, gmax);
  k_ctx<<<dim3(32, 8), 256, 0, stream>>>(Kg, Vg, diagK, proj, gmax, ctx, ksum);
  k_att<<<dim3(8, 8), 256, 0, stream>>>(ids, ln1g, ln1b, Wq, Wk, Wv, proj, hng,
                                        ctx, ksum, x0, att);
  k_fin2<<<8, 256, 0, stream>>>(ln2g, ln2b, Wo, W1, b1, W2, b2, lnfg, lnfb, Wout,
                                bout, Wc1, bc1, Wc2, bc2, x0, att, (float*)d_out);
}

// Round 8
// 147.534 us; speedup vs baseline: 11.6808x; 1.1567x over previous
//
#include <hip/hip_runtime.h>
#include <math.h>

#define NTOK 2048
#define NBF 266
#define MPAD 272

typedef unsigned short u16;
typedef __attribute__((ext_vector_type(8))) short short8;
typedef __attribute__((ext_vector_type(4))) float f32x4;

__device__ __forceinline__ float bf2f(u16 u) {
  unsigned int x = ((unsigned int)u) << 16;
  return __uint_as_float(x);
}
__device__ __forceinline__ u16 f2bf(float f) {
  unsigned int x = __float_as_uint(f);
  unsigned int r = x + 0x7FFFu + ((x >> 16) & 1u);
  return (u16)(r >> 16);
}
__device__ __forceinline__ float wredsum64(float v) {
  for (int o = 32; o > 0; o >>= 1) v += __shfl_xor(v, o);
  return v;
}
__device__ __forceinline__ float bsum256(float v, float* red) {
  for (int o = 32; o > 0; o >>= 1) v += __shfl_xor(v, o);
  __syncthreads();
  if ((threadIdx.x & 63) == 0) red[threadIdx.x >> 6] = v;
  __syncthreads();
  return red[0] + red[1] + red[2] + red[3];
}
__device__ __forceinline__ float bmax256(float v, float* red) {
  for (int o = 32; o > 0; o >>= 1) v = fmaxf(v, __shfl_xor(v, o));
  __syncthreads();
  if ((threadIdx.x & 63) == 0) red[threadIdx.x >> 6] = v;
  __syncthreads();
  return fmaxf(fmaxf(red[0], red[1]), fmaxf(red[2], red[3]));
}
#define INVF_C 0.4152410118609190f

// ---- prep: x, LN1 -> hn (bf16 out), GLOBAL-head K (rotary)+diag, Vg mask ---
__global__ __launch_bounds__(64) void k_prep(
    const int* __restrict__ ids, const float* __restrict__ tok_emb,
    const float* __restrict__ ln1g, const float* __restrict__ ln1b,
    const float* __restrict__ Wk, const float* __restrict__ Wv,
    u16* __restrict__ Kg, u16* __restrict__ Vg, u16* __restrict__ hng,
    float* __restrict__ diagK, float* __restrict__ x0) {
  int blk = blockIdx.x;            // 8 * 256 blocks
  int b = blk >> 8, nt = blk & 255;
  int n0 = nt * 8;
  int t = threadIdx.x;
  __shared__ float hn[8][64];
  int idv[8];
  float g = ln1g[t], bb = ln1b[t];
  float invp = exp2f(-INVF_C * (float)(t & 31));
#pragma unroll
  for (int j = 0; j < 8; ++j) {
    int n = n0 + j;
    int id = ids[b * NTOK + n];
    idv[j] = id;
    float ang = (float)n * invp;
    float pv = (t < 32) ? sinf(ang) : cosf(ang);
    float xv = tok_emb[id * 64 + t] + pv;
    float mu = wredsum64(xv) * 0.015625f;
    float dv = xv - mu;
    float var = wredsum64(dv * dv) * 0.015625f;
    float hv = dv * rsqrtf(var + 1e-5f) * g + bb;
    hn[j][t] = hv;
    hng[((size_t)b * NTOK + n) * 64 + t] = f2bf(hv);
    if (n == 0) x0[b * 64 + t] = xv;
  }
  __syncthreads();

  float acc[8][8];
#pragma unroll
  for (int j = 0; j < 8; ++j)
#pragma unroll
    for (int i = 0; i < 8; ++i) acc[j][i] = 0.f;
  const float* wsrc = (t < 32) ? (Wk + t * 8) : (Wv + (t - 32) * 8);
  for (int d2 = 0; d2 < 64; ++d2) {
    float4 w0 = *reinterpret_cast<const float4*>(wsrc + d2 * 512);
    float4 w1 = *reinterpret_cast<const float4*>(wsrc + d2 * 512 + 4);
#pragma unroll
    for (int j = 0; j < 8; ++j) {
      float hv = hn[j][d2];
      acc[j][0] += hv * w0.x; acc[j][1] += hv * w0.y;
      acc[j][2] += hv * w0.z; acc[j][3] += hv * w0.w;
      acc[j][4] += hv * w1.x; acc[j][5] += hv * w1.y;
      acc[j][6] += hv * w1.z; acc[j][7] += hv * w1.w;
    }
  }

  if (t < 32) {                   // K-global: rotary, diag, write Kg
    int hh = t >> 3, db = (t & 7) * 8;
    float invf[4];
#pragma unroll
    for (int p = 0; p < 4; ++p)
      invf[p] = exp2f(-INVF_C * (float)((db >> 1) + p));
#pragma unroll
    for (int j = 0; j < 8; ++j) {
      int n = n0 + j;
      float kr[8];
#pragma unroll
      for (int p = 0; p < 4; ++p) {
        float ang = (float)n * invf[p];
        float sv = sinf(ang), cv = cosf(ang);
        float e0 = acc[j][2 * p], e1 = acc[j][2 * p + 1];
        kr[2 * p] = e0 * cv - e1 * sv;
        kr[2 * p + 1] = e1 * cv + e0 * sv;
      }
      float dq = 0;
#pragma unroll
      for (int i = 0; i < 8; ++i) dq += kr[i] * kr[i];
      dq += __shfl_xor(dq, 1);
      dq += __shfl_xor(dq, 2);
      dq += __shfl_xor(dq, 4);
      size_t hb = (size_t)(b * 4 + hh) * NTOK + n;
      if ((t & 7) == 0) diagK[hb] = dq * 0.0625f;
      size_t base = hb * 64 + db;
      ushort4 s0, s1;
      s0.x = f2bf(kr[0]); s0.y = f2bf(kr[1]); s0.z = f2bf(kr[2]); s0.w = f2bf(kr[3]);
      s1.x = f2bf(kr[4]); s1.y = f2bf(kr[5]); s1.z = f2bf(kr[6]); s1.w = f2bf(kr[7]);
      *reinterpret_cast<ushort4*>(Kg + base) = s0;
      *reinterpret_cast<ushort4*>(Kg + base + 4) = s1;
    }
  } else {                        // V-global: mask, write Vg
    int tv = t - 32;
    int hh = tv >> 3, db = (tv & 7) * 8;
#pragma unroll
    for (int j = 0; j < 8; ++j) {
      int n = n0 + j;
      float maskf = (idv[j] != 0) ? 1.f : 0.f;
      size_t base = ((size_t)(b * 4 + hh) * NTOK + n) * 64 + db;
      ushort4 m0, m1;
      m0.x = f2bf(acc[j][0] * maskf); m0.y = f2bf(acc[j][1] * maskf);
      m0.z = f2bf(acc[j][2] * maskf); m0.w = f2bf(acc[j][3] * maskf);
      m1.x = f2bf(acc[j][4] * maskf); m1.y = f2bf(acc[j][5] * maskf);
      m1.z = f2bf(acc[j][6] * maskf); m1.w = f2bf(acc[j][7] * maskf);
      *reinterpret_cast<ushort4*>(Vg + base) = m0;
      *reinterpret_cast<ushort4*>(Vg + base + 4) = m1;
    }
  }
}

// ---- stage proj rows [m0, m0+rows) into swizzled bf16 LDS [rows][64] -------
__device__ __forceinline__ void stage_prj(const float* __restrict__ proj,
                                          u16* prjbf, int t, int m0, int rows) {
  for (int c = t; c < rows * 8; c += 256) {
    int r = c >> 3, k0 = (c & 7) * 8;
    int m = m0 + r;
    int e = (r * 64 + k0) ^ ((r & 7) << 3);
    uint4 pk;
    if (m < NBF) {
      const float4* ps = reinterpret_cast<const float4*>(proj + m * 64 + k0);
      float4 p0 = ps[0], p1 = ps[1];
      pk.x = (unsigned)f2bf(p0.x) | ((unsigned)f2bf(p0.y) << 16);
      pk.y = (unsigned)f2bf(p0.z) | ((unsigned)f2bf(p0.w) << 16);
      pk.z = (unsigned)f2bf(p1.x) | ((unsigned)f2bf(p1.y) << 16);
      pk.w = (unsigned)f2bf(p1.z) | ((unsigned)f2bf(p1.w) << 16);
    } else {
      pk.x = pk.y = pk.z = pk.w = 0u;
    }
    *reinterpret_cast<uint4*>(&prjbf[e]) = pk;
  }
}

// ---------------- global max over dash = dn * Kg @ proj^T (MFMA) ------------
// grid (32, 16): 128-row n-slices, 2 chunks of 64
__global__ __launch_bounds__(256) void k_max(
    const u16* __restrict__ Kg, const float* __restrict__ proj,
    unsigned int* __restrict__ gmax) {
  int bh = blockIdx.x, ns = blockIdx.y;
  int t = threadIdx.x, lane = t & 63, w = t >> 6;
  __shared__ __align__(16) u16 prjbf[MPAD * 64];
  __shared__ __align__(16) u16 kbf[64 * 64];
  __shared__ float red[4];
  stage_prj(proj, prjbf, t, 0, MPAD);
  float mv = -3e38f;
  int ko = (lane >> 4) * 8;
  for (int c4 = 0; c4 < 2; ++c4) {
    int nb = ns * 128 + c4 * 64;
    __syncthreads();
    for (int p = 0; p < 2; ++p) {
      int idx = t + p * 256;
      int n = idx >> 3, k0 = (idx & 7) * 8;
      uint4 src = *reinterpret_cast<const uint4*>(
          Kg + ((size_t)bh * NTOK + nb + n) * 64 + k0);
      *reinterpret_cast<uint4*>(&kbf[(n * 64 + k0) ^ ((n & 7) << 3)]) = src;
    }
    __syncthreads();
    int nl = w * 16 + (lane & 15);
    short8 a0 = *reinterpret_cast<const short8*>(&kbf[(nl * 64 + ko) ^ ((nl & 7) << 3)]);
    short8 a1 = *reinterpret_cast<const short8*>(&kbf[(nl * 64 + ko + 32) ^ ((nl & 7) << 3)]);
#pragma unroll
    for (int mt = 0; mt < 17; ++mt) {
      int m = mt * 16 + (lane & 15);
      short8 b0 = *reinterpret_cast<const short8*>(&prjbf[(m * 64 + ko) ^ ((m & 7) << 3)]);
      short8 b1 = *reinterpret_cast<const short8*>(&prjbf[(m * 64 + ko + 32) ^ ((m & 7) << 3)]);
      f32x4 d = {0.f, 0.f, 0.f, 0.f};
      d = __builtin_amdgcn_mfma_f32_16x16x32_bf16(a0, b0, d, 0, 0, 0);
      d = __builtin_amdgcn_mfma_f32_16x16x32_bf16(a1, b1, d, 0, 0, 0);
      if (m < NBF) {
        mv = fmaxf(mv, fmaxf(fmaxf(d[0], d[1]), fmaxf(d[2], d[3])));
      }
    }
  }
  mv *= 0.35355339059327373f;
  for (int o = 32; o > 0; o >>= 1) mv = fmaxf(mv, __shfl_xor(mv, o));
  __syncthreads();
  if (lane == 0) red[w] = mv;
  __syncthreads();
  if (t == 0) {
    float m2 = fmaxf(fmaxf(red[0], red[1]), fmaxf(red[2], red[3]));
    unsigned int b = __float_as_uint(m2);
    unsigned int u = (b & 0x80000000u) ? ~b : (b | 0x80000000u);
    atomicMax(gmax, u);
  }
}

// ---------------- ctx = kp^T @ Vg, ksum = sum_n kp (MFMA) -------------------
// grid (32, 8, 2): z splits the m-dim (rows 0..143 / 144..271) -> ~54KB LDS,
// 2 blocks/CU for latency hiding.
__global__ __launch_bounds__(256) void k_ctx(
    const u16* __restrict__ Kg, const u16* __restrict__ Vg,
    const float* __restrict__ diagK, const float* __restrict__ proj,
    const unsigned int* __restrict__ gmax,
    float* __restrict__ ctx, float* __restrict__ ksum) {
  int bh = blockIdx.x, ns = blockIdx.y, mz = blockIdx.z;
  int m0 = mz * 144;
  int nmt = mz ? 8 : 9;            // 9 tiles (144 rows) / 8 tiles (128 rows)
  int t = threadIdx.x, lane = t & 63, w = t >> 6;
  __shared__ __align__(16) u16 prjbf[144 * 64];
  __shared__ __align__(16) u16 kpT[144 * 64];
  __shared__ __align__(16) u16 kbf[64 * 64];
  __shared__ __align__(16) u16 vbT[64 * 64];
  __shared__ float dg[64];
  __shared__ float ksl[144];
  stage_prj(proj, prjbf, t, m0, 144);
  if (t < 144) ksl[t] = 0.f;
  unsigned int u = *gmax;
  unsigned int bb = (u & 0x80000000u) ? (u & 0x7FFFFFFFu) : ~u;
  float mx = __uint_as_float(bb);
  const float dn = 0.35355339059327373f;
  const float ratio = 1.0f / sqrtf(266.0f);
  int ko = (lane >> 4) * 8;
  f32x4 acc[9];
  float ksacc[9];
#pragma unroll
  for (int i = 0; i < 9; ++i) { acc[i] = (f32x4){0.f, 0.f, 0.f, 0.f}; ksacc[i] = 0.f; }

  for (int c4 = 0; c4 < 4; ++c4) {
    int nb = ns * 256 + c4 * 64;
    for (int p = 0; p < 2; ++p) {
      int idx = t + p * 256;
      int n = idx >> 3, k0 = (idx & 7) * 8;
      uint4 src = *reinterpret_cast<const uint4*>(
          Kg + ((size_t)bh * NTOK + nb + n) * 64 + k0);
      *reinterpret_cast<uint4*>(&kbf[(n * 64 + k0) ^ ((n & 7) << 3)]) = src;
      uint4 vv = *reinterpret_cast<const uint4*>(
          Vg + ((size_t)bh * NTOK + nb + n) * 64 + k0);
      u16 pv[8];
      *reinterpret_cast<uint4*>(pv) = vv;
#pragma unroll
      for (int i = 0; i < 8; ++i) {
        int d = k0 + i;
        vbT[(d * 64 + n) ^ ((d & 7) << 3)] = pv[i];
      }
    }
    if (t < 64) dg[t] = diagK[(size_t)bh * NTOK + nb + t];
    __syncthreads();
    // GEMM1 + exp -> kpT (local rows), ksacc
    {
      int nl = w * 16 + (lane & 15);
      short8 a0 = *reinterpret_cast<const short8*>(&kbf[(nl * 64 + ko) ^ ((nl & 7) << 3)]);
      short8 a1 = *reinterpret_cast<const short8*>(&kbf[(nl * 64 + ko + 32) ^ ((nl & 7) << 3)]);
      float dgv[4];
#pragma unroll
      for (int r = 0; r < 4; ++r) dgv[r] = dg[w * 16 + (lane >> 4) * 4 + r];
      int n0 = w * 16 + (lane >> 4) * 4;
#pragma unroll
      for (int mt = 0; mt < 9; ++mt) {
        if (mt < nmt) {
          int lr = mt * 16 + (lane & 15);
          short8 b0 = *reinterpret_cast<const short8*>(&prjbf[(lr * 64 + ko) ^ ((lr & 7) << 3)]);
          short8 b1 = *reinterpret_cast<const short8*>(&prjbf[(lr * 64 + ko + 32) ^ ((lr & 7) << 3)]);
          f32x4 d = {0.f, 0.f, 0.f, 0.f};
          d = __builtin_amdgcn_mfma_f32_16x16x32_bf16(a0, b0, d, 0, 0, 0);
          d = __builtin_amdgcn_mfma_f32_16x16x32_bf16(a1, b1, d, 0, 0, 0);
          float kp0 = ratio * (expf(dn * d[0] - dgv[0] - mx) + 1e-4f);
          float kp1 = ratio * (expf(dn * d[1] - dgv[1] - mx) + 1e-4f);
          float kp2 = ratio * (expf(dn * d[2] - dgv[2] - mx) + 1e-4f);
          float kp3 = ratio * (expf(dn * d[3] - dgv[3] - mx) + 1e-4f);
          ushort4 pkk;
          pkk.x = f2bf(kp0); pkk.y = f2bf(kp1); pkk.z = f2bf(kp2); pkk.w = f2bf(kp3);
          *reinterpret_cast<ushort4*>(&kpT[(lr * 64 + n0) ^ ((lr & 7) << 3)]) = pkk;
          float ksp = kp0 + kp1 + kp2 + kp3;
          ksp += __shfl_xor(ksp, 16);
          ksp += __shfl_xor(ksp, 32);
          ksacc[mt] += ksp;  // meaningful in lanes 0-15
        }
      }
    }
    __syncthreads();
    // GEMM2: ctx[m][d] += kpT[m][:] * V^T[d][:]
    {
      int dcol = w * 16 + (lane & 15);
      short8 vb0 = *reinterpret_cast<const short8*>(&vbT[(dcol * 64 + ko) ^ ((dcol & 7) << 3)]);
      short8 vb1 = *reinterpret_cast<const short8*>(&vbT[(dcol * 64 + ko + 32) ^ ((dcol & 7) << 3)]);
#pragma unroll
      for (int mt = 0; mt < 9; ++mt) {
        if (mt < nmt) {
          int lr = mt * 16 + (lane & 15);
          short8 a0 = *reinterpret_cast<const short8*>(&kpT[(lr * 64 + ko) ^ ((lr & 7) << 3)]);
          short8 a1 = *reinterpret_cast<const short8*>(&kpT[(lr * 64 + ko + 32) ^ ((lr & 7) << 3)]);
          acc[mt] = __builtin_amdgcn_mfma_f32_16x16x32_bf16(a0, vb0, acc[mt], 0, 0, 0);
          acc[mt] = __builtin_amdgcn_mfma_f32_16x16x32_bf16(a1, vb1, acc[mt], 0, 0, 0);
        }
      }
    }
    __syncthreads();
  }
  // drain ctx + ksum
  int dcol = w * 16 + (lane & 15);
#pragma unroll
  for (int mt = 0; mt < 9; ++mt) {
    if (mt < nmt) {
#pragma unroll
      for (int r = 0; r < 4; ++r) {
        int m = m0 + mt * 16 + (lane >> 4) * 4 + r;
        if (m < NBF)
          atomicAdd(&ctx[((size_t)bh * NBF + m) * 64 + dcol], acc[mt][r]);
      }
      if (lane < 16) atomicAdd(&ksl[mt * 16 + lane], ksacc[mt]);
    }
  }
  __syncthreads();
  if (t < 144 && m0 + t < NBF)
    atomicAdd(&ksum[(size_t)bh * NBF + m0 + t], ksl[t]);
}

// ---------------- attention row 0, one block per (b, head) ------------------
__global__ __launch_bounds__(256) void k_att(
    const int* __restrict__ ids,
    const float* __restrict__ ln1g, const float* __restrict__ ln1b,
    const float* __restrict__ Wq, const float* __restrict__ Wk,
    const float* __restrict__ Wv, const float* __restrict__ proj,
    const u16* __restrict__ hng,
    const float* __restrict__ ctx, const float* __restrict__ ksum,
    const float* __restrict__ x0, float* __restrict__ att) {
  int b = blockIdx.x, h = blockIdx.y;
  int t = threadIdx.x;
  int lane = t & 63, wg = t >> 6;
  __shared__ float hn1[64], qh[64], qpart[4][64], red[4], pol[4][64];
  __shared__ float buf[272];
  __shared__ float dots[2048];
  __shared__ float wkq[64], svec[64];
  __shared__ u16 vst[512 * 64];
  const float dn = 0.35355339059327373f;
  const float ratio = 1.0f / sqrtf(266.0f);

  if (t < 64) {
    float xv = x0[b * 64 + t];
    float mu = wredsum64(xv) * 0.015625f;
    float dv = xv - mu;
    float var = wredsum64(dv * dv) * 0.015625f;
    hn1[t] = dv * rsqrtf(var + 1e-5f) * ln1g[t] + ln1b[t];
  }
  __syncthreads();
  {
    float p = 0;
#pragma unroll
    for (int dd = 0; dd < 16; ++dd)
      p += hn1[wg * 16 + dd] * Wq[(wg * 16 + dd) * 512 + h * 64 + lane];
    qpart[wg][lane] = p;
  }
  __syncthreads();
  if (t < 64) qh[t] = qpart[0][t] + qpart[1][t] + qpart[2][t] + qpart[3][t];
  __syncthreads();

  if (h < 4) {
    // ---- global (Performer) head ----
    int bh = b * 4 + h;
    float dq = 0;
#pragma unroll
    for (int d = 0; d < 64; ++d) dq += qh[d] * qh[d];
    dq *= 0.0625f;
    float lmax = -3e38f;
#pragma unroll
    for (int pass = 0; pass < 2; ++pass) {
      int m = t + pass * 256;
      if (m < NBF) {
        const float4* pp = reinterpret_cast<const float4*>(proj + m * 64);
        float s = 0;
#pragma unroll
        for (int q4 = 0; q4 < 16; ++q4) {
          float4 uu = pp[q4];
          s += qh[q4 * 4] * uu.x + qh[q4 * 4 + 1] * uu.y +
               qh[q4 * 4 + 2] * uu.z + qh[q4 * 4 + 3] * uu.w;
        }
        float dash = dn * s;
        buf[m] = dash;
        lmax = fmaxf(lmax, dash);
      }
    }
    float mxq = bmax256(lmax, red);
    float part = 0;
#pragma unroll
    for (int pass = 0; pass < 2; ++pass) {
      int m = t + pass * 256;
      if (m < NBF) {
        float qp = ratio * (expf(buf[m] - dq - mxq) + 1e-4f);
        buf[m] = qp;
        part += qp * ksum[(size_t)bh * NBF + m];
      }
    }
    float den = bsum256(part, red);
    __syncthreads();
    {
      float s = 0;
      for (int m = wg; m < NBF; m += 4)
        s += buf[m] * ctx[((size_t)bh * NBF + m) * 64 + lane];
      pol[wg][lane] = s;
    }
    __syncthreads();
    if (t < 64)
      att[b * 512 + h * 64 + t] =
          (pol[0][t] + pol[1][t] + pol[2][t] + pol[3][t]) / den;
  } else {
    // ---- local head: dots = hn·(Wk_h q); ol = (Σ p·hn)·Wv_h / Σp ----
    int ch = h * 64;
    if (t < 64) {
      float s = 0;
#pragma unroll 8
      for (int j = 0; j < 64; ++j) s += Wk[t * 512 + ch + j] * qh[j];
      wkq[t] = s;
    }
    __syncthreads();
    const u16* hnb = hng + (size_t)b * NTOK * 64;
    float lmax = -3e38f;
#pragma unroll
    for (int i = 0; i < 8; ++i) {
      int n1 = t + i * 256;
      const ushort4* hr = reinterpret_cast<const ushort4*>(hnb + (size_t)n1 * 64);
      float s = 0;
#pragma unroll
      for (int d4 = 0; d4 < 16; ++d4) {
        ushort4 uu = hr[d4];
        s += wkq[d4 * 4] * bf2f(uu.x) + wkq[d4 * 4 + 1] * bf2f(uu.y) +
             wkq[d4 * 4 + 2] * bf2f(uu.z) + wkq[d4 * 4 + 3] * bf2f(uu.w);
      }
      float dv = s * 0.125f;
      if (ids[b * NTOK + n1] == 0) dv = -1e9f;
      dots[n1] = dv;
      lmax = fmaxf(lmax, dv);
    }
    float mxl = bmax256(lmax, red);
    float ps = 0;
#pragma unroll
    for (int i = 0; i < 8; ++i) {
      int n1 = t + i * 256;
      float p = expf(dots[n1] - mxl);
      dots[n1] = p;
      ps += p;
    }
    float sden = bsum256(ps, red);
    // fold: svec[d] = sum_n p_n hn[n][d] via LDS-staged chunks (coalesced)
    float acc = 0;
    for (int c = 0; c < 4; ++c) {
      __syncthreads();
      const ushort4* src = reinterpret_cast<const ushort4*>(hnb + (size_t)(c * 512) * 64);
      ushort4* dst = reinterpret_cast<ushort4*>(vst);
#pragma unroll
      for (int i = 0; i < 32; ++i) dst[t + i * 256] = src[t + i * 256];
      __syncthreads();
      int r0 = wg * 128;
#pragma unroll 8
      for (int r = 0; r < 128; ++r)
        acc += dots[c * 512 + r0 + r] * bf2f(vst[(r0 + r) * 64 + lane]);
    }
    __syncthreads();
    pol[wg][lane] = acc;
    __syncthreads();
    if (t < 64) svec[t] = pol[0][t] + pol[1][t] + pol[2][t] + pol[3][t];
    __syncthreads();
    {
      float p2 = 0;
#pragma unroll
      for (int dd = 0; dd < 16; ++dd)
        p2 += svec[wg * 16 + dd] * Wv[(wg * 16 + dd) * 512 + ch + lane];
      pol[wg][lane] = p2;
    }
    __syncthreads();
    if (t < 64)
      att[b * 512 + h * 64 + t] =
          (pol[0][t] + pol[1][t] + pol[2][t] + pol[3][t]) / sden;
  }
}

// ---------------- tail at position 0: Wo, FF, final LN, heads ----------------
__global__ __launch_bounds__(256) void k_fin2(
    const float* __restrict__ ln2g, const float* __restrict__ ln2b,
    const float* __restrict__ Wo,
    const float* __restrict__ W1, const float* __restrict__ b1,
    const float* __restrict__ W2, const float* __restrict__ b2,
    const float* __restrict__ lnfg, const float* __restrict__ lnfb,
    const float* __restrict__ Wout, const float* __restrict__ bout,
    const float* __restrict__ Wc1, const float* __restrict__ bc1,
    const float* __restrict__ Wc2, const float* __restrict__ bc2,
    const float* __restrict__ x0, const float* __restrict__ att,
    float* __restrict__ out) {
  int b = blockIdx.x;
  int t = threadIdx.x;
  int lane = t & 63, wg = t >> 6;
  __shared__ float o512s[512], x0s[64], part[4][64];
  __shared__ float y1[64], hn2[64], gact[256], hfin[64], repS[64], c1s[32];
  o512s[t] = att[b * 512 + t];
  o512s[t + 256] = att[b * 512 + t + 256];
  if (t < 64) x0s[t] = x0[b * 64 + t];
  __syncthreads();
  {
    float s = 0;
#pragma unroll 4
    for (int c = wg * 128; c < wg * 128 + 128; ++c) s += o512s[c] * Wo[c * 64 + lane];
    part[wg][lane] = s;
  }
  __syncthreads();
  if (t < 64) {
    float yv = x0s[t] + part[0][t] + part[1][t] + part[2][t] + part[3][t];
    y1[t] = yv;
    float mu = wredsum64(yv) * 0.015625f;
    float dv = yv - mu;
    float var = wredsum64(dv * dv) * 0.015625f;
    hn2[t] = dv * rsqrtf(var + 1e-5f) * ln2g[t] + ln2b[t];
  }
  __syncthreads();
  {
    float s = b1[t];
#pragma unroll 4
    for (int d = 0; d < 64; ++d) s += hn2[d] * W1[d * 256 + t];
    gact[t] = 0.5f * s * (1.f + erff(s * 0.7071067811865475f));
  }
  __syncthreads();
  {
    float s = 0;
#pragma unroll 4
    for (int j = wg * 64; j < wg * 64 + 64; ++j) s += gact[j] * W2[j * 64 + lane];
    part[wg][lane] = s;
  }
  __syncthreads();
  if (t < 64) {
    float y2 = x0s[t] + b2[t] + part[0][t] + part[1][t] + part[2][t] + part[3][t];
    float hm = 0.5f * (y1[t] + y2);
    float mu = wredsum64(hm) * 0.015625f;
    float dv = hm - mu;
    float var = wredsum64(dv * dv) * 0.015625f;
    hfin[t] = dv * rsqrtf(var + 1e-5f) * lnfg[t] + lnfb[t];
  }
  __syncthreads();
  {
    float s = 0;
#pragma unroll
    for (int dd = 0; dd < 16; ++dd)
      s += hfin[wg * 16 + dd] * Wout[(wg * 16 + dd) * 64 + lane];
    part[wg][lane] = s;
  }
  __syncthreads();
  if (t < 64) {
    float s = bout[t] + part[0][t] + part[1][t] + part[2][t] + part[3][t];
    repS[t] = s;
    out[16 + b * 64 + t] = s;
  }
  __syncthreads();
  if (t < 32) {
    float s = bc1[t];
#pragma unroll 4
    for (int d = 0; d < 64; ++d) s += repS[d] * Wc1[d * 32 + t];
    c1s[t] = fmaxf(s, 0.f);
  }
  __syncthreads();
  if (t < 2) {
    float s = bc2[t];
#pragma unroll
    for (int jj = 0; jj < 32; ++jj) s += c1s[jj] * Wc2[jj * 2 + t];
    out[b * 2 + t] = s;
  }
}

extern "C" void kernel_launch(void* const* d_in, const int* in_sizes, int n_in,
                              void* d_out, int out_size, void* d_ws, size_t ws_size,
                              hipStream_t stream) {
  (void)in_sizes; (void)n_in; (void)out_size; (void)ws_size;
  const int* ids = (const int*)d_in[0];
  const float* tok = (const float*)d_in[1];
  const float* ln1g = (const float*)d_in[2];
  const float* ln1b = (const float*)d_in[3];
  const float* Wq = (const float*)d_in[4];
  const float* Wk = (const float*)d_in[5];
  const float* Wv = (const float*)d_in[6];
  const float* Wo = (const float*)d_in[7];
  const float* ln2g = (const float*)d_in[8];
  const float* ln2b = (const float*)d_in[9];
  const float* W1 = (const float*)d_in[10];
  const float* b1 = (const float*)d_in[11];
  const float* W2 = (const float*)d_in[12];
  const float* b2 = (const float*)d_in[13];
  const float* lnfg = (const float*)d_in[14];
  const float* lnfb = (const float*)d_in[15];
  const float* Wout = (const float*)d_in[16];
  const float* bout = (const float*)d_in[17];
  const float* Wc1 = (const float*)d_in[18];
  const float* bc1 = (const float*)d_in[19];
  const float* Wc2 = (const float*)d_in[20];
  const float* bc2 = (const float*)d_in[21];
  const float* proj = (const float*)d_in[22];

  uint8_t* w = (uint8_t*)d_ws;
  size_t off = 0;
  const size_t big = (size_t)8 * 4 * NTOK * 64 * 2;  // 8.39 MB each
  u16* Kg = (u16*)(w + off); off += big;
  u16* Vg = (u16*)(w + off); off += big;
  u16* hng = (u16*)(w + off); off += (size_t)8 * NTOK * 64 * 2;  // 2 MB
  float* diagK = (float*)(w + off); off += (size_t)8 * 4 * NTOK * 4;
  float* ctx = (float*)(w + off); off += (size_t)8 * 4 * NBF * 64 * 4;
  float* ksum = (float*)(w + off); off += (size_t)8 * 4 * NBF * 4;
  unsigned int* gmax = (unsigned int*)(w + off); off += 4;
  float* x0 = (float*)(w + off); off += 64 * 8 * 4;
  float* att = (float*)(w + off); off += (size_t)8 * 512 * 4;

  hipMemsetAsync(ctx, 0,
                 (size_t)8 * 4 * NBF * 64 * 4 + (size_t)8 * 4 * NBF * 4 + 4, stream);
  k_prep<<<8 * 256, 64, 0, stream>>>(ids, tok, ln1g, ln1b, Wk, Wv, Kg, Vg, hng,
                                     diagK, x0);
  k_max<<<dim3(32, 16), 256, 0, stream>>>(Kg, proj, gmax);
  k_ctx<<<dim3(32, 8, 2), 256, 0, stream>>>(Kg, Vg, diagK, proj, gmax, ctx, ksum);
  k_att<<<dim3(8, 8), 256, 0, stream>>>(ids, ln1g, ln1b, Wq, Wk, Wv, proj, hng,
                                        ctx, ksum, x0, att);
  k_fin2<<<8, 256, 0, stream>>>(ln2g, ln2b, Wo, W1, b1, W2, b2, lnfg, lnfb, Wout,
                                bout, Wc1, bc1, Wc2, bc2, x0, att, (float*)d_out);
}